// Round 9
// baseline (7269.028 us; speedup 1.0000x reference)
//
#include <hip/hip_runtime.h>
#include <stdint.h>
#include <stddef.h>

typedef unsigned short u16;
typedef __attribute__((ext_vector_type(8))) short short8;
typedef __attribute__((ext_vector_type(4))) short short4v;
typedef __attribute__((ext_vector_type(4))) float f32x4;

#define DEV static __device__ __forceinline__

DEV float bf2f(u16 u){ return __uint_as_float(((unsigned)u)<<16); }
DEV u16 f2bf(float f){ unsigned x=__float_as_uint(f); return (u16)((x + 0x7fffu + ((x>>16)&1u))>>16); }

DEV float wsum(float v){
#pragma unroll
  for(int o=32;o;o>>=1) v += __shfl_xor(v,o);
  return v;
}
DEV float wmax(float v){
#pragma unroll
  for(int o=32;o;o>>=1) v = fmaxf(v,__shfl_xor(v,o));
  return v;
}
DEV float sigm(float x){ return __fdividef(1.f, 1.f+__expf(-x)); }
DEV float tanhx(float x){ float e=__expf(-2.f*fabsf(x)); float t=__fdividef(1.f-e,1.f+e); return x<0.f?-t:t; }

DEV f32x4 mfma16(short8 a, short8 b, f32x4 c){
  asm("v_mfma_f32_16x16x32_bf16 %0, %1, %2, %0" : "+v"(c) : "v"(a), "v"(b));
  return c;
}
DEV void gll16(const void* g, void* l){
  __builtin_amdgcn_global_load_lds((const __attribute__((address_space(1))) void*)g,
                                   (__attribute__((address_space(3))) void*)l, 16, 0, 0);
}

DEV void pack8(u16* dst, const float* src){
  const float4 a=*(const float4*)(src);
  const float4 b=*(const float4*)(src+4);
  short8 o;
  o[0]=(short)f2bf(a.x); o[1]=(short)f2bf(a.y); o[2]=(short)f2bf(a.z); o[3]=(short)f2bf(a.w);
  o[4]=(short)f2bf(b.x); o[5]=(short)f2bf(b.y); o[6]=(short)f2bf(b.z); o[7]=(short)f2bf(b.w);
  *(short8*)dst=o;
}
DEV void zero8(u16* dst){
  short8 z;
#pragma unroll
  for(int e=0;e<8;++e) z[e]=0;
  *(short8*)dst=z;
}

// Flag-array global barrier (256 blocks, 1/CU co-resident). Each block sets
// its own flag (no atomic contention); block 0 polls all flags in parallel,
// then releases `gen`. Coherence pattern (threadfence + agent acquire/release)
// is the one hardware-validated in round 8.
DEV void gbarF(unsigned* flags, unsigned* gen, unsigned target){
  __syncthreads();
  if (blockIdx.x==0){
    const int tid=threadIdx.x;
    if (tid>=1 && tid<256){
      while(__hip_atomic_load(&flags[tid],__ATOMIC_ACQUIRE,__HIP_MEMORY_SCOPE_AGENT)<target)
        __builtin_amdgcn_s_sleep(1);
    }
    __syncthreads();
    if (tid==0){
      __threadfence();
      __hip_atomic_store(gen,target,__ATOMIC_RELEASE,__HIP_MEMORY_SCOPE_AGENT);
    }
  } else {
    if (threadIdx.x==0){
      __threadfence();
      __hip_atomic_store(&flags[blockIdx.x],target,__ATOMIC_RELEASE,__HIP_MEMORY_SCOPE_AGENT);
      while(__hip_atomic_load(gen,__ATOMIC_ACQUIRE,__HIP_MEMORY_SCOPE_AGENT)<target)
        __builtin_amdgcn_s_sleep(1);
      __threadfence();
    }
  }
  __syncthreads();
}

// ---------------------------------------------------------------------------
// setup: fp32->bf16 casts, weight reorders, embedding gather, combined bias.
// Gate rows unit-major: new row r <-> orig row o=((r&3)<<9)+(r>>2).
// ---------------------------------------------------------------------------
__global__ __launch_bounds__(256) void setup_cast(
  const float* __restrict__ feats, const int* __restrict__ captions,
  const float* __restrict__ embW, const float* __restrict__ Wf_w,
  const float* __restrict__ Wh_w, const float* __restrict__ W_ih,
  const float* __restrict__ W_hh, const float* __restrict__ b_ih,
  const float* __restrict__ b_hh, const float* __restrict__ out_w,
  u16* __restrict__ feats_bf, u16* __restrict__ outw_bf, u16* __restrict__ Wc,
  u16* __restrict__ WihE, u16* __restrict__ embx, u16* __restrict__ Whw_bf,
  u16* __restrict__ Wf_bf, float* __restrict__ bias_comb)
{
  const long long o0=12845056LL,o1=28246016LL,o2=30343168LL,o3=31391744LL,
                  o4=32702464LL,o5=32964608LL,o6=33226752LL,total=33228800LL;
  for (long long i8=((long long)blockIdx.x*256+threadIdx.x)*8; i8<total;
       i8+=(long long)gridDim.x*256*8){
    const long long i=i8;
    if (i<o0){ pack8(feats_bf+i, feats+i); }
    else if (i<o1){ const long long j=i-o0; const int r=(int)(j>>9);
      if (r<30000) pack8(outw_bf+j, out_w+j); else zero8(outw_bf+j); }
    else if (i<o2){ const long long j=i-o1; const int r=(int)(j>>10), k=(int)(j&1023);
      const int o=((r&3)<<9)+(r>>2);
      const float* s=(k<512)? (W_ih+(size_t)o*1024+512+k) : (W_hh+(size_t)o*512+(k-512));
      pack8(Wc+j, s); }
    else if (i<o3){ const long long j=i-o2; const int r=(int)(j>>9), k=(int)(j&511);
      const int o=((r&3)<<9)+(r>>2);
      pack8(WihE+j, W_ih+(size_t)o*1024+k); }
    else if (i<o4){ const long long j=i-o3; const int m=(int)(j>>9), e=(int)(j&511);
      const int b=m/20, tt=m-b*20; const int idx=captions[b*21+tt];
      if (idx) pack8(embx+j, embW+(size_t)idx*512+e); else zero8(embx+j); }
    else if (i<o5){ const long long j=i-o4; pack8(Whw_bf+j, Wh_w+j); }
    else if (i<o6){ const long long j=i-o5; pack8(Wf_bf+j, Wf_w+j); }
    else { const long long j=i-o6;
      for(int e=0;e<8;++e){ const int r=(int)(j+e); const int o=((r&3)<<9)+(r>>2);
        bias_comb[r]=b_ih[o]+b_hh[o]; } }
  }
}

// ---------------------------------------------------------------------------
// prep: gfeat = mean(feats), h0/c0. h0 (bf16) -> xs h-slot, c0 (fp32) -> cbuf.
// ---------------------------------------------------------------------------
__global__ __launch_bounds__(256) void prep(
  const float* __restrict__ feats, const float* __restrict__ init_w,
  const float* __restrict__ init_b, const float* __restrict__ initc_w,
  const float* __restrict__ initc_b, u16* __restrict__ xs0, float* __restrict__ cbuf)
{
  const int b=blockIdx.x, tid=threadIdx.x, lane=tid&63, w=tid>>6;
  __shared__ float gf[512];
  const float* fb=feats+(size_t)b*196*512;
  float a0=0.f,a1=0.f;
  for(int n=0;n<196;++n){ a0+=fb[(size_t)n*512+tid]; a1+=fb[(size_t)n*512+tid+256]; }
  gf[tid]=a0*(1.f/196.f); gf[tid+256]=a1*(1.f/196.f);
  __syncthreads();
  const int kb=lane*8;
  float g8[8];
#pragma unroll
  for(int e=0;e<8;++e) g8[e]=gf[kb+e];
  for(int j=w*128;j<w*128+128;++j){
    const float* r1=init_w+(size_t)j*512+kb;
    const float* r2=initc_w+(size_t)j*512+kb;
    float s1=0.f,s2=0.f;
#pragma unroll
    for(int e=0;e<8;++e){ s1+=g8[e]*r1[e]; s2+=g8[e]*r2[e]; }
    s1=wsum(s1); s2=wsum(s2);
    if(lane==(j&63)){ xs0[b*1024+512+j]=f2bf(s1+init_b[j]); cbuf[b*512+j]=s2+initc_b[j]; }
  }
}

// ---------------------------------------------------------------------------
// mega2: 20-step recurrence, 256 blocks x 512 threads (8 waves), 4 phases/step.
//  A (256 blk, pair (b=blk>>1,h=blk&1)): hproj (redundant per pair, r1 rows) +
//    scores for rows [98h,98h+98) with 4-row load batching -> sc_g[b][n].
//  B (256 blk): softmax(196) (r1 code, reading sc_g) + ctx for cols
//    [256h,256h+256) over all 196 rows (short4 coalesced) -> xs ctx cols.
//  C1 (blk<64): r7 gemm<4> body (kz=blk>>4,nt=blk&15; waves 0-3 compute,
//    4-7 barrier-only) -> gpart[4][128][2048].
//  C2 (blk<128): r7 LSTM prologue -> cbuf, xs h-slot, h_all[t].
// ---------------------------------------------------------------------------
__global__ __launch_bounds__(512,2) void mega2(
  const u16* __restrict__ fproj, const u16* __restrict__ feats_bf,
  u16* __restrict__ xs, const u16* __restrict__ Whw,
  const float* __restrict__ Whb, const float* __restrict__ vw,
  const float* __restrict__ vb, const float* __restrict__ gemb,
  float* __restrict__ gpart, float* __restrict__ cbuf,
  u16* __restrict__ h_all, const u16* __restrict__ Wc,
  float* __restrict__ sc_g, unsigned* __restrict__ flags,
  unsigned* __restrict__ gen)
{
  const int blk=blockIdx.x, tid=threadIdx.x, lane=tid&63, w=tid>>6;
  const int b=blk>>1, h=blk&1;
  const int kzC=blk>>4, ntC=blk&15;
  __shared__ float hsf[512], hp[512], scw[208], red[8];
  __shared__ float part[8][256];
  __shared__ u16 As[128*32], Bs[128*32];
  const int kb=lane*8;
  unsigned tgt=0;

  for(int t=0;t<20;++t){
    // ================= Phase A: hproj + scores =================
    hsf[tid]=bf2f(xs[b*1024+512+tid]);
    __syncthreads();
    float h8[8];
#pragma unroll
    for(int e=0;e<8;++e) h8[e]=hsf[kb+e];
    // hproj: wave w owns rows [w*64, w*64+64)  (r1-proven)
    for(int j=w*64;j<w*64+64;++j){
      short8 wv=*(const short8*)(Whw+(size_t)j*512+kb);
      float s=0.f;
#pragma unroll
      for(int e=0;e<8;++e) s+=h8[e]*bf2f((u16)wv[e]);
      s=wsum(s);
      if(lane==(j&63)) hp[j]=s+Whb[j];
    }
    __syncthreads();
    // scores: v·tanh(f+p) = v - 2v/(exp(2(f+p))+1); 4-row batching for MLP
    float p2[8], vm2[8];
    float sv=0.f;
#pragma unroll
    for(int e=0;e<8;++e){
      const float p=hp[kb+e], v=vw[kb+e];
      p2[e]=2.f*p; vm2[e]=-2.f*v; sv+=v;
    }
    const float vb0=vb[0];
    const int base=h*98;
#pragma unroll
    for(int i=0;i<12;i+=4){
      const int n0=base+w+8*i;
      short8 f0=*(const short8*)(fproj+((size_t)b*196+n0   )*512+kb);
      short8 f1=*(const short8*)(fproj+((size_t)b*196+n0+8 )*512+kb);
      short8 f2=*(const short8*)(fproj+((size_t)b*196+n0+16)*512+kb);
      short8 f3=*(const short8*)(fproj+((size_t)b*196+n0+24)*512+kb);
      float s0=sv,s1=sv,s2=sv,s3=sv;
#pragma unroll
      for(int e=0;e<8;++e){
        s0+=__fdividef(vm2[e],__expf(fmaf(bf2f((u16)f0[e]),2.f,p2[e]))+1.f);
        s1+=__fdividef(vm2[e],__expf(fmaf(bf2f((u16)f1[e]),2.f,p2[e]))+1.f);
        s2+=__fdividef(vm2[e],__expf(fmaf(bf2f((u16)f2[e]),2.f,p2[e]))+1.f);
        s3+=__fdividef(vm2[e],__expf(fmaf(bf2f((u16)f3[e]),2.f,p2[e]))+1.f);
      }
      s0=wsum(s0); s1=wsum(s1); s2=wsum(s2); s3=wsum(s3);
      if(lane==0){
        sc_g[b*224+n0   ]=s0+vb0;
        sc_g[b*224+n0+8 ]=s1+vb0;
        sc_g[b*224+n0+16]=s2+vb0;
        sc_g[b*224+n0+24]=s3+vb0;
      }
    }
    if (w<2){
      const int n=base+96+w;
      short8 f0=*(const short8*)(fproj+((size_t)b*196+n)*512+kb);
      float s0=sv;
#pragma unroll
      for(int e=0;e<8;++e)
        s0+=__fdividef(vm2[e],__expf(fmaf(bf2f((u16)f0[e]),2.f,p2[e]))+1.f);
      s0=wsum(s0);
      if(lane==0) sc_g[b*224+n]=s0+vb0;
    }
    gbarF(flags,gen,++tgt);

    // ================= Phase B: softmax + ctx (cols) =================
    float xv=(tid<196)? sc_g[b*224+tid] : -3.0e38f;
    float mx=wmax(xv);
    if(lane==0) red[w]=mx;
    __syncthreads();
    float mm=red[0];
#pragma unroll
    for(int i=1;i<8;++i) mm=fmaxf(mm,red[i]);
    float pv=(tid<196)? __expf(xv-mm) : 0.f;
    float ps=wsum(pv);
    __syncthreads();
    if(lane==0) red[w]=ps;
    __syncthreads();
    float tot=red[0];
#pragma unroll
    for(int i=1;i<8;++i) tot+=red[i];
    if(tid<196) scw[tid]=__fdividef(pv,tot);
    __syncthreads();
    // ctx: cols [256h, 256h+256), rows n = w + 8i (all 196)
    float4 acc; acc.x=0.f; acc.y=0.f; acc.z=0.f; acc.w=0.f;
    const int cb=h*256+lane*4;
#pragma unroll
    for(int i=0;i<24;i+=2){
      const int n0=w+8*i, n1=n0+8;
      short4v v0=*(const short4v*)(feats_bf+((size_t)b*196+n0)*512+cb);
      short4v v1=*(const short4v*)(feats_bf+((size_t)b*196+n1)*512+cb);
      const float w0=scw[n0], w1=scw[n1];
      acc.x+=w0*bf2f((u16)v0[0])+w1*bf2f((u16)v1[0]);
      acc.y+=w0*bf2f((u16)v0[1])+w1*bf2f((u16)v1[1]);
      acc.z+=w0*bf2f((u16)v0[2])+w1*bf2f((u16)v1[2]);
      acc.w+=w0*bf2f((u16)v0[3])+w1*bf2f((u16)v1[3]);
    }
    {
      const int n=w+192;
      if (n<196){
        short4v v0=*(const short4v*)(feats_bf+((size_t)b*196+n)*512+cb);
        const float w0=scw[n];
        acc.x+=w0*bf2f((u16)v0[0]);
        acc.y+=w0*bf2f((u16)v0[1]);
        acc.z+=w0*bf2f((u16)v0[2]);
        acc.w+=w0*bf2f((u16)v0[3]);
      }
    }
    *(float4*)&part[w][lane*4]=acc;
    __syncthreads();
    if (tid<256){
      float s=0.f;
#pragma unroll
      for(int i=0;i<8;++i) s+=part[i][tid];
      xs[b*1024 + h*256 + tid]=f2bf(s);
    }
    gbarF(flags,gen,++tgt);

    // ================= Phase C1: gates partial (blocks 0..63) =================
    if (blk<64){
      const u16* Ap=xs+(size_t)kzC*256;
      const u16* Bp=Wc+(size_t)kzC*256;
      const int bn=ntC*128;
      f32x4 acc2[4][4]={};
      const int srow=tid>>2, scol=(tid&3)*8;
      const int wr=(w>>1)*64, wc2=(w&1)*64;
      const int ro=lane&15, ko=(lane>>4)*8;
      for(int k0=0;k0<256;k0+=32){
        if (w<4){
          gll16(Ap+(size_t)(srow)*1024    +k0+scol, As+tid*8);
          gll16(Ap+(size_t)(64+srow)*1024 +k0+scol, As+2048+tid*8);
          gll16(Bp+(size_t)(bn+srow)*1024    +k0+scol, Bs+tid*8);
          gll16(Bp+(size_t)(bn+64+srow)*1024 +k0+scol, Bs+2048+tid*8);
        }
        __syncthreads();
        if (w<4){
          short8 af[4], bfr[4];
#pragma unroll
          for(int m=0;m<4;++m) af[m]=*(const short8*)(As+(wr+m*16+ro)*32+ko);
#pragma unroll
          for(int n=0;n<4;++n) bfr[n]=*(const short8*)(Bs+(wc2+n*16+ro)*32+ko);
#pragma unroll
          for(int m=0;m<4;++m)
#pragma unroll
            for(int n=0;n<4;++n) acc2[m][n]=mfma16(af[m],bfr[n],acc2[m][n]);
        }
        __syncthreads();
      }
      if (w<4){
        asm volatile("s_nop 7\ns_nop 7\ns_nop 7");
        const int ro4=(lane>>4)*4, co=lane&15;
#pragma unroll
        for(int m=0;m<4;++m)
#pragma unroll
          for(int n=0;n<4;++n)
#pragma unroll
            for(int j=0;j<4;++j){
              const int r=wr+m*16+ro4+j, c=bn+wc2+n*16+co;
              gpart[((size_t)kzC*128+r)*2048+c]=acc2[m][n][j];
            }
      }
    }
    gbarF(flags,gen,++tgt);

    // ================= Phase C2: LSTM (blocks 0..127) =================
    if (blk<128){
      const int b2=blk, u=tid;
      float4 g4=*(const float4*)&gemb[((size_t)b2*20+t)*2048+u*4];
#pragma unroll
      for(int kz=0;kz<4;++kz){
        const float4 p=*(const float4*)&gpart[((size_t)kz*128+b2)*2048+u*4];
        g4.x+=p.x; g4.y+=p.y; g4.z+=p.z; g4.w+=p.w;
      }
      const float cn=sigm(g4.y)*cbuf[b2*512+u]+sigm(g4.x)*tanhx(g4.z);
      const float hn=sigm(g4.w)*tanhx(cn);
      cbuf[b2*512+u]=cn;
      const u16 hb=f2bf(hn);
      xs[b2*1024+512+u]=hb;
      h_all[((size_t)b2*20+t)*512+u]=hb;
    }
    gbarF(flags,gen,++tgt);
  }
}

// ---------------------------------------------------------------------------
// gemm_bt: C[M,N] = A[M,K] * B[N,K]^T, 128x128 tile, m97 structure.
// MODE 0: bf16 out + bias   MODE 1: f32 out + bias   MODE 2: f32 + col guard
// ---------------------------------------------------------------------------
template<int MODE>
__global__ __launch_bounds__(256) void gemm_bt(
  const u16* __restrict__ A, int lda, const u16* __restrict__ Bw, int ldb, int K,
  const float* __restrict__ bias, float* __restrict__ outf, u16* __restrict__ outb,
  int ncols)
{
  const int bm=blockIdx.y*128, bn=blockIdx.x*128;
  const int tid=threadIdx.x, lane=tid&63, wave=tid>>6;
  const int wr=(wave>>1)*64, wc=(wave&1)*64;
  __shared__ u16 As[128*32], Bs[128*32];
  f32x4 acc[4][4]={};
  const int srow=tid>>2, scol=(tid&3)*8;
  for(int k0=0;k0<K;k0+=32){
    gll16(A +(size_t)(bm+srow)*lda    +k0+scol, As+tid*8);
    gll16(A +(size_t)(bm+64+srow)*lda +k0+scol, As+2048+tid*8);
    gll16(Bw+(size_t)(bn+srow)*ldb    +k0+scol, Bs+tid*8);
    gll16(Bw+(size_t)(bn+64+srow)*ldb +k0+scol, Bs+2048+tid*8);
    __syncthreads();
    short8 af[4], bfr[4];
    const int ro=lane&15, ko=(lane>>4)*8;
#pragma unroll
    for(int m=0;m<4;++m) af[m]=*(const short8*)(As+(wr+m*16+ro)*32+ko);
#pragma unroll
    for(int n=0;n<4;++n) bfr[n]=*(const short8*)(Bs+(wc+n*16+ro)*32+ko);
#pragma unroll
    for(int m=0;m<4;++m)
#pragma unroll
      for(int n=0;n<4;++n) acc[m][n]=mfma16(af[m],bfr[n],acc[m][n]);
    __syncthreads();
  }
  asm volatile("s_nop 7\ns_nop 7\ns_nop 7");  // MFMA->VALU hazard guard
  const int ro4=(lane>>4)*4, co=lane&15;
#pragma unroll
  for(int m=0;m<4;++m)
#pragma unroll
    for(int n=0;n<4;++n)
#pragma unroll
      for(int j=0;j<4;++j){
        const int r=bm+wr+m*16+ro4+j, c=bn+wc+n*16+co;
        if constexpr (MODE==0)      outb[(size_t)r*ncols+c]=f2bf(acc[m][n][j]+bias[c]);
        else if constexpr (MODE==1) outf[(size_t)r*ncols+c]=acc[m][n][j]+bias[c];
        else { if (c<ncols) outf[(size_t)r*ncols+c]=acc[m][n][j]+bias[c]; }
      }
}

// ---------------------------------------------------------------------------
extern "C" void kernel_launch(void* const* d_in, const int* in_sizes, int n_in,
                              void* d_out, int out_size, void* d_ws, size_t ws_size,
                              hipStream_t stream) {
  const float* feats   =(const float*)d_in[0];
  const int*   captions=(const int*)  d_in[1];
  const float* embW    =(const float*)d_in[2];
  const float* Wf_w    =(const float*)d_in[3];
  const float* Wf_b    =(const float*)d_in[4];
  const float* Wh_w    =(const float*)d_in[5];
  const float* Wh_b    =(const float*)d_in[6];
  const float* v_w     =(const float*)d_in[7];
  const float* v_b     =(const float*)d_in[8];
  const float* W_ih    =(const float*)d_in[9];
  const float* W_hh    =(const float*)d_in[10];
  const float* b_ih    =(const float*)d_in[11];
  const float* b_hh    =(const float*)d_in[12];
  const float* init_w  =(const float*)d_in[13];
  const float* init_b  =(const float*)d_in[14];
  const float* initc_w =(const float*)d_in[15];
  const float* initc_b =(const float*)d_in[16];
  const float* out_w   =(const float*)d_in[17];
  const float* out_b   =(const float*)d_in[18];
  float* out=(float*)d_out;
  char* ws=(char*)d_ws;

  u16*   feats_bf =(u16*)  (ws+0);
  u16*   fproj    =(u16*)  (ws+25690112);
  u16*   outw_bf  =(u16*)  (ws+51380224);
  u16*   Wc       =(u16*)  (ws+82182144);
  u16*   WihE     =(u16*)  (ws+86376448);
  u16*   Whw_bf   =(u16*)  (ws+88473600);
  u16*   Wf_bf    =(u16*)  (ws+88997888);
  u16*   embx     =(u16*)  (ws+89522176);
  u16*   h_all    =(u16*)  (ws+92143616);
  u16*   xs0      =(u16*)  (ws+94765056);
  float* gemb     =(float*)(ws+95289344);
  float* cbuf     =(float*)(ws+116260864);
  float* bias_comb=(float*)(ws+116523008);
  float* gpart    =(float*)(ws+116531200);   // 4 x 128 x 2048 f32 = 4 MB
  float* sc_g     =(float*)(ws+120725504);   // 128 x 224 f32
  unsigned* flags =(unsigned*)(ws+120840192); // 256 u32
  unsigned* gen   =(unsigned*)(ws+120841216);

  hipMemsetAsync(flags, 0, 2048, stream);
  setup_cast<<<4096,256,0,stream>>>(feats,captions,embW,Wf_w,Wh_w,W_ih,W_hh,b_ih,b_hh,out_w,
                                    feats_bf,outw_bf,Wc,WihE,embx,Whw_bf,Wf_bf,bias_comb);
  prep<<<128,256,0,stream>>>(feats,init_w,init_b,initc_w,initc_b,xs0,cbuf);
  // fproj = feats_bf @ Wf^T + Wf_b  (25088 x 512, K=512) -> bf16
  gemm_bt<0><<<dim3(4,196),256,0,stream>>>(feats_bf,512,Wf_bf,512,512,
      Wf_b,nullptr,fproj,512);
  // gemb = embx @ WihE^T + (b_ih+b_hh)  (2560 x 2048, K=512) -> f32
  gemm_bt<1><<<dim3(16,20),256,0,stream>>>(embx,512,WihE,512,512,
      bias_comb,gemb,nullptr,2048);

  // whole 20-step recurrence: 256 blocks x 512 threads, 4 phases/step
  mega2<<<256,512,0,stream>>>(fproj,feats_bf,xs0,Whw_bf,Wh_b,v_w,v_b,
                              gemb,gpart,cbuf,h_all,Wc,sc_g,flags,gen);

  // logits = h_all @ out_w^T + out_b  (2560 x 30016->30000, K=512) -> d_out
  gemm_bt<2><<<dim3(235,20),256,0,stream>>>(h_all,512,outw_bf,512,512,
      out_b,out,nullptr,30000);
}

// Round 10
// 1341.893 us; speedup vs baseline: 5.4170x; 5.4170x over previous
//
#include <hip/hip_runtime.h>
#include <stdint.h>
#include <stddef.h>

typedef unsigned short u16;
typedef __attribute__((ext_vector_type(8))) short short8;
typedef __attribute__((ext_vector_type(4))) short short4v;
typedef __attribute__((ext_vector_type(4))) float f32x4;

#define DEV static __device__ __forceinline__

DEV float bf2f(u16 u){ return __uint_as_float(((unsigned)u)<<16); }
DEV u16 f2bf(float f){ unsigned x=__float_as_uint(f); return (u16)((x + 0x7fffu + ((x>>16)&1u))>>16); }

DEV float wsum(float v){
#pragma unroll
  for(int o=32;o;o>>=1) v += __shfl_xor(v,o);
  return v;
}
DEV float wmax(float v){
#pragma unroll
  for(int o=32;o;o>>=1) v = fmaxf(v,__shfl_xor(v,o));
  return v;
}
DEV float sigm(float x){ return __fdividef(1.f, 1.f+__expf(-x)); }
DEV float tanhx(float x){ float e=__expf(-2.f*fabsf(x)); float t=__fdividef(1.f-e,1.f+e); return x<0.f?-t:t; }

DEV f32x4 mfma16(short8 a, short8 b, f32x4 c){
  asm("v_mfma_f32_16x16x32_bf16 %0, %1, %2, %0" : "+v"(c) : "v"(a), "v"(b));
  return c;
}
DEV void gll16(const void* g, void* l){
  __builtin_amdgcn_global_load_lds((const __attribute__((address_space(1))) void*)g,
                                   (__attribute__((address_space(3))) void*)l, 16, 0, 0);
}

DEV void pack8(u16* dst, const float* src){
  const float4 a=*(const float4*)(src);
  const float4 b=*(const float4*)(src+4);
  short8 o;
  o[0]=(short)f2bf(a.x); o[1]=(short)f2bf(a.y); o[2]=(short)f2bf(a.z); o[3]=(short)f2bf(a.w);
  o[4]=(short)f2bf(b.x); o[5]=(short)f2bf(b.y); o[6]=(short)f2bf(b.z); o[7]=(short)f2bf(b.w);
  *(short8*)dst=o;
}
DEV void zero8(u16* dst){
  short8 z;
#pragma unroll
  for(int e=0;e<8;++e) z[e]=0;
  *(short8*)dst=z;
}

// ---------------------------------------------------------------------------
// setup: fp32->bf16 casts, weight reorders, embedding gather, combined bias.
// Gate rows unit-major: new row r <-> orig row o=((r&3)<<9)+(r>>2).
// ---------------------------------------------------------------------------
__global__ __launch_bounds__(256) void setup_cast(
  const float* __restrict__ feats, const int* __restrict__ captions,
  const float* __restrict__ embW, const float* __restrict__ Wf_w,
  const float* __restrict__ Wh_w, const float* __restrict__ W_ih,
  const float* __restrict__ W_hh, const float* __restrict__ b_ih,
  const float* __restrict__ b_hh, const float* __restrict__ out_w,
  u16* __restrict__ feats_bf, u16* __restrict__ outw_bf, u16* __restrict__ Wc,
  u16* __restrict__ WihE, u16* __restrict__ embx, u16* __restrict__ Whw_bf,
  u16* __restrict__ Wf_bf, float* __restrict__ bias_comb)
{
  const long long o0=12845056LL,o1=28246016LL,o2=30343168LL,o3=31391744LL,
                  o4=32702464LL,o5=32964608LL,o6=33226752LL,total=33228800LL;
  for (long long i8=((long long)blockIdx.x*256+threadIdx.x)*8; i8<total;
       i8+=(long long)gridDim.x*256*8){
    const long long i=i8;
    if (i<o0){ pack8(feats_bf+i, feats+i); }
    else if (i<o1){ const long long j=i-o0; const int r=(int)(j>>9);
      if (r<30000) pack8(outw_bf+j, out_w+j); else zero8(outw_bf+j); }
    else if (i<o2){ const long long j=i-o1; const int r=(int)(j>>10), k=(int)(j&1023);
      const int o=((r&3)<<9)+(r>>2);
      const float* s=(k<512)? (W_ih+(size_t)o*1024+512+k) : (W_hh+(size_t)o*512+(k-512));
      pack8(Wc+j, s); }
    else if (i<o3){ const long long j=i-o2; const int r=(int)(j>>9), k=(int)(j&511);
      const int o=((r&3)<<9)+(r>>2);
      pack8(WihE+j, W_ih+(size_t)o*1024+k); }
    else if (i<o4){ const long long j=i-o3; const int m=(int)(j>>9), e=(int)(j&511);
      const int b=m/20, tt=m-b*20; const int idx=captions[b*21+tt];
      if (idx) pack8(embx+j, embW+(size_t)idx*512+e); else zero8(embx+j); }
    else if (i<o5){ const long long j=i-o4; pack8(Whw_bf+j, Wh_w+j); }
    else if (i<o6){ const long long j=i-o5; pack8(Wf_bf+j, Wf_w+j); }
    else { const long long j=i-o6;
      for(int e=0;e<8;++e){ const int r=(int)(j+e); const int o=((r&3)<<9)+(r>>2);
        bias_comb[r]=b_ih[o]+b_hh[o]; } }
  }
}

// ---------------------------------------------------------------------------
// prep: gfeat = mean(feats), h0/c0. h0 (bf16) -> xs h-slot, c0 -> cbuf[0].
// ---------------------------------------------------------------------------
__global__ __launch_bounds__(256) void prep(
  const float* __restrict__ feats, const float* __restrict__ init_w,
  const float* __restrict__ init_b, const float* __restrict__ initc_w,
  const float* __restrict__ initc_b, u16* __restrict__ xs0, float* __restrict__ cbuf)
{
  const int b=blockIdx.x, tid=threadIdx.x, lane=tid&63, w=tid>>6;
  __shared__ float gf[512];
  const float* fb=feats+(size_t)b*196*512;
  float a0=0.f,a1=0.f;
  for(int n=0;n<196;++n){ a0+=fb[(size_t)n*512+tid]; a1+=fb[(size_t)n*512+tid+256]; }
  gf[tid]=a0*(1.f/196.f); gf[tid+256]=a1*(1.f/196.f);
  __syncthreads();
  const int kb=lane*8;
  float g8[8];
#pragma unroll
  for(int e=0;e<8;++e) g8[e]=gf[kb+e];
  for(int j=w*128;j<w*128+128;++j){
    const float* r1=init_w+(size_t)j*512+kb;
    const float* r2=initc_w+(size_t)j*512+kb;
    float s1=0.f,s2=0.f;
#pragma unroll
    for(int e=0;e<8;++e){ s1+=g8[e]*r1[e]; s2+=g8[e]*r2[e]; }
    s1=wsum(s1); s2=wsum(s2);
    if(lane==(j&63)){ xs0[b*1024+512+j]=f2bf(s1+init_b[j]); cbuf[b*512+j]=s2+initc_b[j]; }
  }
}

// ---------------------------------------------------------------------------
// attn_sc: 256 blocks x 512 threads, block = (b=blk>>1, h=blk&1).
// Prologue (t>0): LSTM for t-1 (redundant per pair; cbuf ping-pong buffers so
// both blocks read the OLD buffer and write the NEW one -> no race; written
// values bit-identical). Writes h(t-1) -> xs h-slot, h_all, LDS hsf.
// Then hproj (full, redundant; proven 2-row-ILP body, 8-wave bounds) and
// scores for rows [98h, 98h+98) (proven 4-row-batched body) -> sc_g raw.
// ---------------------------------------------------------------------------
__global__ __launch_bounds__(512) void attn_sc(
  const u16* __restrict__ fproj, u16* __restrict__ xs,
  const u16* __restrict__ Whw, const float* __restrict__ Whb,
  const float* __restrict__ vw, const float* __restrict__ vb,
  const float* __restrict__ gemb, const float* __restrict__ gpart,
  float* __restrict__ cbuf, u16* __restrict__ h_all,
  float* __restrict__ sc_g, int t)
{
  const int blk=blockIdx.x, tid=threadIdx.x, lane=tid&63, w=tid>>6;
  const int b=blk>>1, h=blk&1;
  __shared__ float hsf[512], hp[512];
  if (t>0){
    const int u=tid;
    float4 g4=*(const float4*)&gemb[((size_t)b*20+(t-1))*2048+u*4];
#pragma unroll
    for(int kz=0;kz<4;++kz){
      const float4 p=*(const float4*)&gpart[((size_t)kz*128+b)*2048+u*4];
      g4.x+=p.x; g4.y+=p.y; g4.z+=p.z; g4.w+=p.w;
    }
    const float cold=cbuf[((t-1)&1)*65536 + b*512+u];
    const float cn=sigm(g4.y)*cold+sigm(g4.x)*tanhx(g4.z);
    const float hn=sigm(g4.w)*tanhx(cn);
    cbuf[(t&1)*65536 + b*512+u]=cn;
    const u16 hb=f2bf(hn);
    xs[b*1024+512+u]=hb;
    h_all[((size_t)b*20+(t-1))*512+u]=hb;
    hsf[u]=bf2f(hb);
  } else {
    hsf[tid]=bf2f(xs[b*1024+512+tid]);
  }
  __syncthreads();
  const int kb=lane*8;
  float h8[8];
#pragma unroll
  for(int e=0;e<8;++e) h8[e]=hsf[kb+e];
  // hproj: wave w owns rows [64w, 64w+64), 2 rows per iteration (proven body)
  for(int jj=0;jj<64;jj+=2){
    const int j=w*64+jj;
    short8 w0=*(const short8*)(Whw+(size_t)j*512+kb);
    short8 w1=*(const short8*)(Whw+(size_t)(j+1)*512+kb);
    float s0=0.f,s1=0.f;
#pragma unroll
    for(int e=0;e<8;++e){
      s0+=h8[e]*bf2f((u16)w0[e]);
      s1+=h8[e]*bf2f((u16)w1[e]);
    }
    s0=wsum(s0); s1=wsum(s1);
    if(lane==0){ hp[j]=s0+Whb[j]; hp[j+1]=s1+Whb[j+1]; }
  }
  __syncthreads();
  // scores: v·tanh(f+p) = v - 2v/(exp(2(f+p))+1); 4-row batching (proven)
  float p2[8], vm2[8];
  float sv=0.f;
#pragma unroll
  for(int e=0;e<8;++e){
    const float p=hp[kb+e], v=vw[kb+e];
    p2[e]=2.f*p; vm2[e]=-2.f*v; sv+=v;
  }
  const float vb0=vb[0];
  const int base=h*98;
#pragma unroll
  for(int i=0;i<12;i+=4){
    const int n0=base+w+8*i;
    short8 f0=*(const short8*)(fproj+((size_t)b*196+n0   )*512+kb);
    short8 f1=*(const short8*)(fproj+((size_t)b*196+n0+8 )*512+kb);
    short8 f2=*(const short8*)(fproj+((size_t)b*196+n0+16)*512+kb);
    short8 f3=*(const short8*)(fproj+((size_t)b*196+n0+24)*512+kb);
    float s0=sv,s1=sv,s2=sv,s3=sv;
#pragma unroll
    for(int e=0;e<8;++e){
      s0+=__fdividef(vm2[e],__expf(fmaf(bf2f((u16)f0[e]),2.f,p2[e]))+1.f);
      s1+=__fdividef(vm2[e],__expf(fmaf(bf2f((u16)f1[e]),2.f,p2[e]))+1.f);
      s2+=__fdividef(vm2[e],__expf(fmaf(bf2f((u16)f2[e]),2.f,p2[e]))+1.f);
      s3+=__fdividef(vm2[e],__expf(fmaf(bf2f((u16)f3[e]),2.f,p2[e]))+1.f);
    }
    s0=wsum(s0); s1=wsum(s1); s2=wsum(s2); s3=wsum(s3);
    if(lane==0){
      sc_g[b*224+n0   ]=s0+vb0;
      sc_g[b*224+n0+8 ]=s1+vb0;
      sc_g[b*224+n0+16]=s2+vb0;
      sc_g[b*224+n0+24]=s3+vb0;
    }
  }
  if (w<2){
    const int n=base+96+w;
    short8 f0=*(const short8*)(fproj+((size_t)b*196+n)*512+kb);
    float s0=sv;
#pragma unroll
    for(int e=0;e<8;++e)
      s0+=__fdividef(vm2[e],__expf(fmaf(bf2f((u16)f0[e]),2.f,p2[e]))+1.f);
    s0=wsum(s0);
    if(lane==0) sc_g[b*224+n]=s0+vb0;
  }
}

// ---------------------------------------------------------------------------
// ctx_step: 256 blocks x 512 threads, block = (b=blk>>1, h=blk&1).
// softmax(196) over sc_g (redundant per pair; proven 8-wave body), then ctx
// for cols [256h, 256h+256) over all 196 rows (proven body) -> xs ctx cols.
// ---------------------------------------------------------------------------
__global__ __launch_bounds__(512) void ctx_step(
  const u16* __restrict__ feats_bf, u16* __restrict__ xs,
  const float* __restrict__ sc_g)
{
  const int blk=blockIdx.x, tid=threadIdx.x, lane=tid&63, w=tid>>6;
  const int b=blk>>1, h=blk&1;
  __shared__ float scw[208], red[8];
  __shared__ float part[8][256];
  float xv=(tid<196)? sc_g[b*224+tid] : -3.0e38f;
  float mx=wmax(xv);
  if(lane==0) red[w]=mx;
  __syncthreads();
  float mm=red[0];
#pragma unroll
  for(int i=1;i<8;++i) mm=fmaxf(mm,red[i]);
  float pv=(tid<196)? __expf(xv-mm) : 0.f;
  float ps=wsum(pv);
  __syncthreads();
  if(lane==0) red[w]=ps;
  __syncthreads();
  float tot=red[0];
#pragma unroll
  for(int i=1;i<8;++i) tot+=red[i];
  if(tid<196) scw[tid]=__fdividef(pv,tot);
  __syncthreads();
  // ctx: cols [256h, 256h+256), rows n = w + 8i (all 196)
  float4 acc; acc.x=0.f; acc.y=0.f; acc.z=0.f; acc.w=0.f;
  const int cb=h*256+lane*4;
#pragma unroll
  for(int i=0;i<24;i+=2){
    const int n0=w+8*i, n1=n0+8;
    short4v v0=*(const short4v*)(feats_bf+((size_t)b*196+n0)*512+cb);
    short4v v1=*(const short4v*)(feats_bf+((size_t)b*196+n1)*512+cb);
    const float w0=scw[n0], w1=scw[n1];
    acc.x+=w0*bf2f((u16)v0[0])+w1*bf2f((u16)v1[0]);
    acc.y+=w0*bf2f((u16)v0[1])+w1*bf2f((u16)v1[1]);
    acc.z+=w0*bf2f((u16)v0[2])+w1*bf2f((u16)v1[2]);
    acc.w+=w0*bf2f((u16)v0[3])+w1*bf2f((u16)v1[3]);
  }
  {
    const int n=w+192;
    if (n<196){
      short4v v0=*(const short4v*)(feats_bf+((size_t)b*196+n)*512+cb);
      const float w0=scw[n];
      acc.x+=w0*bf2f((u16)v0[0]);
      acc.y+=w0*bf2f((u16)v0[1]);
      acc.z+=w0*bf2f((u16)v0[2]);
      acc.w+=w0*bf2f((u16)v0[3]);
    }
  }
  *(float4*)&part[w][lane*4]=acc;
  __syncthreads();
  if (tid<256){
    float s=0.f;
#pragma unroll
    for(int i=0;i<8;++i) s+=part[i][tid];
    xs[b*1024 + h*256 + tid]=f2bf(s);
  }
}

// ---------------------------------------------------------------------------
// lstm_fin: LSTM for the final step (t=19) — h_all only. Reads cbuf[1] (c18).
// ---------------------------------------------------------------------------
__global__ __launch_bounds__(512) void lstm_fin(
  const float* __restrict__ gemb, const float* __restrict__ gpart,
  const float* __restrict__ cbuf, u16* __restrict__ h_all)
{
  const int b=blockIdx.x, u=threadIdx.x;
  float4 g4=*(const float4*)&gemb[((size_t)b*20+19)*2048+u*4];
#pragma unroll
  for(int kz=0;kz<4;++kz){
    const float4 p=*(const float4*)&gpart[((size_t)kz*128+b)*2048+u*4];
    g4.x+=p.x; g4.y+=p.y; g4.z+=p.z; g4.w+=p.w;
  }
  const float cn=sigm(g4.y)*cbuf[65536 + b*512+u]+sigm(g4.x)*tanhx(g4.z);
  const float hn=sigm(g4.w)*tanhx(cn);
  h_all[((size_t)b*20+19)*512+u]=f2bf(hn);
}

// ---------------------------------------------------------------------------
// gemm_bt: C[M,N] = A[M,K] * B[N,K]^T, 128x128 tile, m97 structure.
// MODE 0: bf16 out + bias   MODE 1: f32 out + bias
// MODE 2: f32 + col guard, TRANSPOSED GRID (x = row tile, y = col tile) so
//         consecutive blocks share a B column-tile -> L2 reuse of out_w.
// MODE 4: K-split partial (blockIdx.y = kz, base += kz*256, bm=0)
// ---------------------------------------------------------------------------
template<int MODE>
__global__ __launch_bounds__(256) void gemm_bt(
  const u16* __restrict__ A, int lda, const u16* __restrict__ Bw, int ldb, int K,
  const float* __restrict__ bias, float* __restrict__ outf, u16* __restrict__ outb,
  int ncols)
{
  const int bm=(MODE==4)? 0 : ((MODE==2)? blockIdx.x*128 : blockIdx.y*128);
  const int bn=(MODE==2)? blockIdx.y*128 : blockIdx.x*128;
  const int kz=(MODE==4)? blockIdx.y : 0;
  const u16* __restrict__ Ap=A +(size_t)kz*256;
  const u16* __restrict__ Bp=Bw+(size_t)kz*256;
  const int tid=threadIdx.x, lane=tid&63, wave=tid>>6;
  const int wr=(wave>>1)*64, wc=(wave&1)*64;
  __shared__ u16 As[128*32], Bs[128*32];
  f32x4 acc[4][4]={};
  const int srow=tid>>2, scol=(tid&3)*8;
  for(int k0=0;k0<K;k0+=32){
    gll16(Ap+(size_t)(bm+srow)*lda    +k0+scol, As+tid*8);
    gll16(Ap+(size_t)(bm+64+srow)*lda +k0+scol, As+2048+tid*8);
    gll16(Bp+(size_t)(bn+srow)*ldb    +k0+scol, Bs+tid*8);
    gll16(Bp+(size_t)(bn+64+srow)*ldb +k0+scol, Bs+2048+tid*8);
    __syncthreads();
    short8 af[4], bfr[4];
    const int ro=lane&15, ko=(lane>>4)*8;
#pragma unroll
    for(int m=0;m<4;++m) af[m]=*(const short8*)(As+(wr+m*16+ro)*32+ko);
#pragma unroll
    for(int n=0;n<4;++n) bfr[n]=*(const short8*)(Bs+(wc+n*16+ro)*32+ko);
#pragma unroll
    for(int m=0;m<4;++m)
#pragma unroll
      for(int n=0;n<4;++n) acc[m][n]=mfma16(af[m],bfr[n],acc[m][n]);
    __syncthreads();
  }
  asm volatile("s_nop 7\ns_nop 7\ns_nop 7");  // MFMA->VALU hazard guard
  const int ro4=(lane>>4)*4, co=lane&15;
#pragma unroll
  for(int m=0;m<4;++m)
#pragma unroll
    for(int n=0;n<4;++n)
#pragma unroll
      for(int j=0;j<4;++j){
        const int r=bm+wr+m*16+ro4+j, c=bn+wc+n*16+co;
        if constexpr (MODE==0)      outb[(size_t)r*ncols+c]=f2bf(acc[m][n][j]+bias[c]);
        else if constexpr (MODE==1) outf[(size_t)r*ncols+c]=acc[m][n][j]+bias[c];
        else if constexpr (MODE==2){ if (c<ncols) outf[(size_t)r*ncols+c]=acc[m][n][j]+bias[c]; }
        else                        outf[((size_t)kz*128+r)*ncols+c]=acc[m][n][j];
      }
}

// ---------------------------------------------------------------------------
extern "C" void kernel_launch(void* const* d_in, const int* in_sizes, int n_in,
                              void* d_out, int out_size, void* d_ws, size_t ws_size,
                              hipStream_t stream) {
  const float* feats   =(const float*)d_in[0];
  const int*   captions=(const int*)  d_in[1];
  const float* embW    =(const float*)d_in[2];
  const float* Wf_w    =(const float*)d_in[3];
  const float* Wf_b    =(const float*)d_in[4];
  const float* Wh_w    =(const float*)d_in[5];
  const float* Wh_b    =(const float*)d_in[6];
  const float* v_w     =(const float*)d_in[7];
  const float* v_b     =(const float*)d_in[8];
  const float* W_ih    =(const float*)d_in[9];
  const float* W_hh    =(const float*)d_in[10];
  const float* b_ih    =(const float*)d_in[11];
  const float* b_hh    =(const float*)d_in[12];
  const float* init_w  =(const float*)d_in[13];
  const float* init_b  =(const float*)d_in[14];
  const float* initc_w =(const float*)d_in[15];
  const float* initc_b =(const float*)d_in[16];
  const float* out_w   =(const float*)d_in[17];
  const float* out_b   =(const float*)d_in[18];
  float* out=(float*)d_out;
  char* ws=(char*)d_ws;

  u16*   feats_bf =(u16*)  (ws+0);
  u16*   fproj    =(u16*)  (ws+25690112);
  u16*   outw_bf  =(u16*)  (ws+51380224);
  u16*   Wc       =(u16*)  (ws+82182144);
  u16*   WihE     =(u16*)  (ws+86376448);
  u16*   Whw_bf   =(u16*)  (ws+88473600);
  u16*   Wf_bf    =(u16*)  (ws+88997888);
  u16*   embx     =(u16*)  (ws+89522176);
  u16*   h_all    =(u16*)  (ws+92143616);
  u16*   xs0      =(u16*)  (ws+94765056);
  float* gemb     =(float*)(ws+95289344);
  float* cbuf     =(float*)(ws+116260864);  // 2 x 128 x 512 f32 (ping-pong)
  float* bias_comb=(float*)(ws+116785152);
  float* gpart    =(float*)(ws+116793344);  // 4 x 128 x 2048 f32 = 4 MB
  float* sc_g     =(float*)(ws+120987648);  // 128 x 224 f32

  setup_cast<<<4096,256,0,stream>>>(feats,captions,embW,Wf_w,Wh_w,W_ih,W_hh,b_ih,b_hh,out_w,
                                    feats_bf,outw_bf,Wc,WihE,embx,Whw_bf,Wf_bf,bias_comb);
  prep<<<128,256,0,stream>>>(feats,init_w,init_b,initc_w,initc_b,xs0,cbuf);
  // fproj = feats_bf @ Wf^T + Wf_b  (25088 x 512, K=512) -> bf16
  gemm_bt<0><<<dim3(4,196),256,0,stream>>>(feats_bf,512,Wf_bf,512,512,
      Wf_b,nullptr,fproj,512);
  // gemb = embx @ WihE^T + (b_ih+b_hh)  (2560 x 2048, K=512) -> f32
  gemm_bt<1><<<dim3(16,20),256,0,stream>>>(embx,512,WihE,512,512,
      bias_comb,gemb,nullptr,2048);

  for(int t=0;t<20;++t){
    attn_sc<<<256,512,0,stream>>>(fproj,xs0,Whw_bf,Wh_b,v_w,v_b,
                                  gemb,gpart,cbuf,h_all,sc_g,t);
    ctx_step<<<256,512,0,stream>>>(feats_bf,xs0,sc_g);
    // gates partials: xs(128x1024) @ Wc^T(2048x1024), K-split 4x256 -> gpart
    gemm_bt<4><<<dim3(16,4),256,0,stream>>>(xs0,1024,Wc,1024,256,
        nullptr,gpart,nullptr,2048);
  }
  lstm_fin<<<128,512,0,stream>>>(gemb,gpart,cbuf,h_all);
  // logits = h_all @ out_w^T + out_b, transposed grid for out_w L2 reuse
  gemm_bt<2><<<dim3(20,235),256,0,stream>>>(h_all,512,outw_bf,512,512,
      out_b,out,nullptr,30000);
}

// Round 12
// 1171.602 us; speedup vs baseline: 6.2044x; 1.1453x over previous
//
#include <hip/hip_runtime.h>
#include <stdint.h>
#include <stddef.h>

typedef unsigned short u16;
typedef __attribute__((ext_vector_type(8))) short short8;
typedef __attribute__((ext_vector_type(4))) float f32x4;

#define DEV static __device__ __forceinline__

DEV float bf2f(u16 u){ return __uint_as_float(((unsigned)u)<<16); }
DEV u16 f2bf(float f){ unsigned x=__float_as_uint(f); return (u16)((x + 0x7fffu + ((x>>16)&1u))>>16); }

DEV float wsum(float v){
#pragma unroll
  for(int o=32;o;o>>=1) v += __shfl_xor(v,o);
  return v;
}
DEV float wmax(float v){
#pragma unroll
  for(int o=32;o;o>>=1) v = fmaxf(v,__shfl_xor(v,o));
  return v;
}
DEV float sigm(float x){ return __fdividef(1.f, 1.f+__expf(-x)); }
DEV float tanhx(float x){ float e=__expf(-2.f*fabsf(x)); float t=__fdividef(1.f-e,1.f+e); return x<0.f?-t:t; }

DEV f32x4 mfma16(short8 a, short8 b, f32x4 c){
  asm("v_mfma_f32_16x16x32_bf16 %0, %1, %2, %0" : "+v"(c) : "v"(a), "v"(b));
  return c;
}
DEV void gll16(const void* g, void* l){
  __builtin_amdgcn_global_load_lds((const __attribute__((address_space(1))) void*)g,
                                   (__attribute__((address_space(3))) void*)l, 16, 0, 0);
}

DEV void pack8(u16* dst, const float* src){
  const float4 a=*(const float4*)(src);
  const float4 b=*(const float4*)(src+4);
  short8 o;
  o[0]=(short)f2bf(a.x); o[1]=(short)f2bf(a.y); o[2]=(short)f2bf(a.z); o[3]=(short)f2bf(a.w);
  o[4]=(short)f2bf(b.x); o[5]=(short)f2bf(b.y); o[6]=(short)f2bf(b.z); o[7]=(short)f2bf(b.w);
  *(short8*)dst=o;
}
DEV void zero8(u16* dst){
  short8 z;
#pragma unroll
  for(int e=0;e<8;++e) z[e]=0;
  *(short8*)dst=z;
}

// ---------------------------------------------------------------------------
// setup: fp32->bf16 casts, weight reorders, embedding gather, combined bias.
// Gate rows unit-major: new row r <-> orig row o=((r&3)<<9)+(r>>2).
// ---------------------------------------------------------------------------
__global__ __launch_bounds__(256) void setup_cast(
  const float* __restrict__ feats, const int* __restrict__ captions,
  const float* __restrict__ embW, const float* __restrict__ Wf_w,
  const float* __restrict__ Wh_w, const float* __restrict__ W_ih,
  const float* __restrict__ W_hh, const float* __restrict__ b_ih,
  const float* __restrict__ b_hh, const float* __restrict__ out_w,
  u16* __restrict__ feats_bf, u16* __restrict__ outw_bf, u16* __restrict__ Wc,
  u16* __restrict__ WihE, u16* __restrict__ embx, u16* __restrict__ Whw_bf,
  u16* __restrict__ Wf_bf, float* __restrict__ bias_comb)
{
  const long long o0=12845056LL,o1=28246016LL,o2=30343168LL,o3=31391744LL,
                  o4=32702464LL,o5=32964608LL,o6=33226752LL,total=33228800LL;
  for (long long i8=((long long)blockIdx.x*256+threadIdx.x)*8; i8<total;
       i8+=(long long)gridDim.x*256*8){
    const long long i=i8;
    if (i<o0){ pack8(feats_bf+i, feats+i); }
    else if (i<o1){ const long long j=i-o0; const int r=(int)(j>>9);
      if (r<30000) pack8(outw_bf+j, out_w+j); else zero8(outw_bf+j); }
    else if (i<o2){ const long long j=i-o1; const int r=(int)(j>>10), k=(int)(j&1023);
      const int o=((r&3)<<9)+(r>>2);
      const float* s=(k<512)? (W_ih+(size_t)o*1024+512+k) : (W_hh+(size_t)o*512+(k-512));
      pack8(Wc+j, s); }
    else if (i<o3){ const long long j=i-o2; const int r=(int)(j>>9), k=(int)(j&511);
      const int o=((r&3)<<9)+(r>>2);
      pack8(WihE+j, W_ih+(size_t)o*1024+k); }
    else if (i<o4){ const long long j=i-o3; const int m=(int)(j>>9), e=(int)(j&511);
      const int b=m/20, tt=m-b*20; const int idx=captions[b*21+tt];
      if (idx) pack8(embx+j, embW+(size_t)idx*512+e); else zero8(embx+j); }
    else if (i<o5){ const long long j=i-o4; pack8(Whw_bf+j, Wh_w+j); }
    else if (i<o6){ const long long j=i-o5; pack8(Wf_bf+j, Wf_w+j); }
    else { const long long j=i-o6;
      for(int e=0;e<8;++e){ const int r=(int)(j+e); const int o=((r&3)<<9)+(r>>2);
        bias_comb[r]=b_ih[o]+b_hh[o]; } }
  }
}

// ---------------------------------------------------------------------------
// prep: gfeat = mean(feats), h0/c0. h0 (bf16) -> xs h-slot, c0 (fp32) -> cbuf.
// ---------------------------------------------------------------------------
__global__ __launch_bounds__(256) void prep(
  const float* __restrict__ feats, const float* __restrict__ init_w,
  const float* __restrict__ init_b, const float* __restrict__ initc_w,
  const float* __restrict__ initc_b, u16* __restrict__ xs0, float* __restrict__ cbuf)
{
  const int b=blockIdx.x, tid=threadIdx.x, lane=tid&63, w=tid>>6;
  __shared__ float gf[512];
  const float* fb=feats+(size_t)b*196*512;
  float a0=0.f,a1=0.f;
  for(int n=0;n<196;++n){ a0+=fb[(size_t)n*512+tid]; a1+=fb[(size_t)n*512+tid+256]; }
  gf[tid]=a0*(1.f/196.f); gf[tid+256]=a1*(1.f/196.f);
  __syncthreads();
  const int kb=lane*8;
  float g8[8];
#pragma unroll
  for(int e=0;e<8;++e) g8[e]=gf[kb+e];
  for(int j=w*128;j<w*128+128;++j){
    const float* r1=init_w+(size_t)j*512+kb;
    const float* r2=initc_w+(size_t)j*512+kb;
    float s1=0.f,s2=0.f;
#pragma unroll
    for(int e=0;e<8;++e){ s1+=g8[e]*r1[e]; s2+=g8[e]*r2[e]; }
    s1=wsum(s1); s2=wsum(s2);
    if(lane==(j&63)){ xs0[b*1024+512+j]=f2bf(s1+init_b[j]); cbuf[b*512+j]=s2+initc_b[j]; }
  }
}

// ---------------------------------------------------------------------------
// attn_step: 128 blocks x 1024 threads (16 waves), r7 fused structure with
// 4-row load batching in hproj/scores/ctx (bisection subject of r12).
// Prologue (t>0): LSTM for step t-1 (4 gpart K-slices).
// ---------------------------------------------------------------------------
__global__ __launch_bounds__(1024) void attn_step(
  const u16* __restrict__ fproj, const u16* __restrict__ feats_bf,
  u16* __restrict__ xs, const u16* __restrict__ Whw,
  const float* __restrict__ Whb, const float* __restrict__ vw,
  const float* __restrict__ vb, const float* __restrict__ gemb,
  const float* __restrict__ gpart, float* __restrict__ cbuf,
  u16* __restrict__ h_all, int t)
{
  const int b=blockIdx.x, tid=threadIdx.x, lane=tid&63, w=tid>>6;
  __shared__ float part[16][512];
  __shared__ float hsf[512], hp[512], sc[208], red[16];
  if (t>0){
    if (tid<512){
      const int u=tid;
      float4 g4=*(const float4*)&gemb[((size_t)b*20+(t-1))*2048+u*4];
#pragma unroll
      for(int kz=0;kz<4;++kz){
        const float4 p=*(const float4*)&gpart[((size_t)kz*128+b)*2048+u*4];
        g4.x+=p.x; g4.y+=p.y; g4.z+=p.z; g4.w+=p.w;
      }
      const float cn=sigm(g4.y)*cbuf[b*512+u]+sigm(g4.x)*tanhx(g4.z);
      const float hn=sigm(g4.w)*tanhx(cn);
      cbuf[b*512+u]=cn;
      const u16 hb=f2bf(hn);
      xs[b*1024+512+u]=hb;
      h_all[((size_t)b*20+(t-1))*512+u]=hb;
      hsf[u]=bf2f(hb);
    }
  } else {
    if (tid<512) hsf[tid]=bf2f(xs[b*1024+512+tid]);
  }
  __syncthreads();
  const int kb=lane*8;
  float h8[8];
#pragma unroll
  for(int e=0;e<8;++e) h8[e]=hsf[kb+e];
  // hproj: wave w owns rows [32w, 32w+32), 4 rows per iteration
#pragma unroll
  for(int jj=0;jj<32;jj+=4){
    const int j=w*32+jj;
    short8 w0=*(const short8*)(Whw+(size_t)j*512+kb);
    short8 w1=*(const short8*)(Whw+(size_t)(j+1)*512+kb);
    short8 w2=*(const short8*)(Whw+(size_t)(j+2)*512+kb);
    short8 w3=*(const short8*)(Whw+(size_t)(j+3)*512+kb);
    float s0=0.f,s1=0.f,s2=0.f,s3=0.f;
#pragma unroll
    for(int e=0;e<8;++e){
      const float he=h8[e];
      s0+=he*bf2f((u16)w0[e]);
      s1+=he*bf2f((u16)w1[e]);
      s2+=he*bf2f((u16)w2[e]);
      s3+=he*bf2f((u16)w3[e]);
    }
    s0=wsum(s0); s1=wsum(s1); s2=wsum(s2); s3=wsum(s3);
    if(lane==0){ hp[j]=s0+Whb[j]; hp[j+1]=s1+Whb[j+1];
                 hp[j+2]=s2+Whb[j+2]; hp[j+3]=s3+Whb[j+3]; }
  }
  __syncthreads();
  // scores: v·tanh(f+p) = v - 2v/(exp(2(f+p))+1); 4-row batching
  float p2[8], vm2[8];
  float sv=0.f;
#pragma unroll
  for(int e=0;e<8;++e){
    const float p=hp[kb+e], v=vw[kb+e];
    p2[e]=2.f*p; vm2[e]=-2.f*v; sv+=v;
  }
  const float vb0=vb[0];
#pragma unroll
  for(int i=0;i<12;i+=4){
    const int n0=w+16*i;
    short8 f0=*(const short8*)(fproj+((size_t)b*196+n0   )*512+kb);
    short8 f1=*(const short8*)(fproj+((size_t)b*196+n0+16)*512+kb);
    short8 f2=*(const short8*)(fproj+((size_t)b*196+n0+32)*512+kb);
    short8 f3=*(const short8*)(fproj+((size_t)b*196+n0+48)*512+kb);
    float s0=sv,s1=sv,s2=sv,s3=sv;
#pragma unroll
    for(int e=0;e<8;++e){
      s0+=__fdividef(vm2[e],__expf(fmaf(bf2f((u16)f0[e]),2.f,p2[e]))+1.f);
      s1+=__fdividef(vm2[e],__expf(fmaf(bf2f((u16)f1[e]),2.f,p2[e]))+1.f);
      s2+=__fdividef(vm2[e],__expf(fmaf(bf2f((u16)f2[e]),2.f,p2[e]))+1.f);
      s3+=__fdividef(vm2[e],__expf(fmaf(bf2f((u16)f3[e]),2.f,p2[e]))+1.f);
    }
    s0=wsum(s0); s1=wsum(s1); s2=wsum(s2); s3=wsum(s3);
    if(lane==0){
      sc[n0   ]=s0+vb0;
      sc[n0+16]=s1+vb0;
      sc[n0+32]=s2+vb0;
      sc[n0+48]=s3+vb0;
    }
  }
  {
    const int n=w+192;
    if (n<196){
      short8 f0=*(const short8*)(fproj+((size_t)b*196+n)*512+kb);
      float s0=sv;
#pragma unroll
      for(int e=0;e<8;++e)
        s0+=__fdividef(vm2[e],__expf(fmaf(bf2f((u16)f0[e]),2.f,p2[e]))+1.f);
      s0=wsum(s0);
      if(lane==0) sc[n]=s0+vb0;
    }
  }
  __syncthreads();
  // softmax over 196
  float xv=(tid<196)? sc[tid] : -3.0e38f;
  float mx=wmax(xv);
  if(lane==0) red[w]=mx;
  __syncthreads();
  float mm=red[0];
#pragma unroll
  for(int i=1;i<16;++i) mm=fmaxf(mm,red[i]);
  float pv=(tid<196)? __expf(xv-mm) : 0.f;
  float ps=wsum(pv);
  __syncthreads();
  if(lane==0) red[w]=ps;
  __syncthreads();
  float tot=red[0];
#pragma unroll
  for(int i=1;i<16;++i) tot+=red[i];
  if(tid<196) sc[tid]=__fdividef(pv,tot);
  __syncthreads();
  // ctx partials: wave w accumulates rows w+16i, 4-row batching
  float a8[8];
#pragma unroll
  for(int e=0;e<8;++e) a8[e]=0.f;
#pragma unroll
  for(int i=0;i<12;i+=4){
    const int n0=w+16*i;
    short8 v0=*(const short8*)(feats_bf+((size_t)b*196+n0   )*512+kb);
    short8 v1=*(const short8*)(feats_bf+((size_t)b*196+n0+16)*512+kb);
    short8 v2=*(const short8*)(feats_bf+((size_t)b*196+n0+32)*512+kb);
    short8 v3=*(const short8*)(feats_bf+((size_t)b*196+n0+48)*512+kb);
    const float wn0=sc[n0], wn1=sc[n0+16], wn2=sc[n0+32], wn3=sc[n0+48];
#pragma unroll
    for(int e=0;e<8;++e)
      a8[e]+=wn0*bf2f((u16)v0[e])+wn1*bf2f((u16)v1[e])
            +wn2*bf2f((u16)v2[e])+wn3*bf2f((u16)v3[e]);
  }
  {
    const int n=w+192;
    if (n<196){
      short8 v0=*(const short8*)(feats_bf+((size_t)b*196+n)*512+kb);
      const float wn=sc[n];
#pragma unroll
      for(int e=0;e<8;++e) a8[e]+=wn*bf2f((u16)v0[e]);
    }
  }
  *(float4*)&part[w][kb]  =*(float4*)&a8[0];
  *(float4*)&part[w][kb+4]=*(float4*)&a8[4];
  __syncthreads();
  if (tid<512){
    float s=0.f;
#pragma unroll
    for(int i=0;i<16;++i) s+=part[i][tid];
    xs[b*1024+tid]=f2bf(s);
  }
}

// ---------------------------------------------------------------------------
// lstm_fin: LSTM for the final step (t=19) — h_all only.
// ---------------------------------------------------------------------------
__global__ __launch_bounds__(512) void lstm_fin(
  const float* __restrict__ gemb, const float* __restrict__ gpart,
  const float* __restrict__ cbuf, u16* __restrict__ h_all)
{
  const int b=blockIdx.x, u=threadIdx.x;
  float4 g4=*(const float4*)&gemb[((size_t)b*20+19)*2048+u*4];
#pragma unroll
  for(int kz=0;kz<4;++kz){
    const float4 p=*(const float4*)&gpart[((size_t)kz*128+b)*2048+u*4];
    g4.x+=p.x; g4.y+=p.y; g4.z+=p.z; g4.w+=p.w;
  }
  const float cn=sigm(g4.y)*cbuf[b*512+u]+sigm(g4.x)*tanhx(g4.z);
  const float hn=sigm(g4.w)*tanhx(cn);
  h_all[((size_t)b*20+19)*512+u]=f2bf(hn);
}

// ---------------------------------------------------------------------------
// gemm_bt: C[M,N] = A[M,K] * B[N,K]^T, 128x128 tile, m97 structure.
// MODE 0: bf16 out + bias   MODE 1: f32 out + bias
// MODE 2: f32 + col guard, TRANSPOSED GRID (x = row tile, y = col tile) so
//         consecutive blocks share a B column-tile -> L2 reuse of out_w.
// MODE 4: K-split partial (blockIdx.y = kz, base += kz*256, bm=0) — the
//         r7/r10-PROVEN gates path.
// ---------------------------------------------------------------------------
template<int MODE>
__global__ __launch_bounds__(256) void gemm_bt(
  const u16* __restrict__ A, int lda, const u16* __restrict__ Bw, int ldb, int K,
  const float* __restrict__ bias, float* __restrict__ outf, u16* __restrict__ outb,
  int ncols)
{
  const int bm=(MODE==4)? 0 : ((MODE==2)? blockIdx.x*128 : blockIdx.y*128);
  const int bn=(MODE==2)? blockIdx.y*128 : blockIdx.x*128;
  const int kz=(MODE==4)? blockIdx.y : 0;
  const u16* __restrict__ Ap=A +(size_t)kz*256;
  const u16* __restrict__ Bp=Bw+(size_t)kz*256;
  const int tid=threadIdx.x, lane=tid&63, wave=tid>>6;
  const int wr=(wave>>1)*64, wc=(wave&1)*64;
  __shared__ u16 As[128*32], Bs[128*32];
  f32x4 acc[4][4]={};
  const int srow=tid>>2, scol=(tid&3)*8;
  for(int k0=0;k0<K;k0+=32){
    gll16(Ap+(size_t)(bm+srow)*lda    +k0+scol, As+tid*8);
    gll16(Ap+(size_t)(bm+64+srow)*lda +k0+scol, As+2048+tid*8);
    gll16(Bp+(size_t)(bn+srow)*ldb    +k0+scol, Bs+tid*8);
    gll16(Bp+(size_t)(bn+64+srow)*ldb +k0+scol, Bs+2048+tid*8);
    __syncthreads();
    short8 af[4], bfr[4];
    const int ro=lane&15, ko=(lane>>4)*8;
#pragma unroll
    for(int m=0;m<4;++m) af[m]=*(const short8*)(As+(wr+m*16+ro)*32+ko);
#pragma unroll
    for(int n=0;n<4;++n) bfr[n]=*(const short8*)(Bs+(wc+n*16+ro)*32+ko);
#pragma unroll
    for(int m=0;m<4;++m)
#pragma unroll
      for(int n=0;n<4;++n) acc[m][n]=mfma16(af[m],bfr[n],acc[m][n]);
    __syncthreads();
  }
  asm volatile("s_nop 7\ns_nop 7\ns_nop 7");  // MFMA->VALU hazard guard
  const int ro4=(lane>>4)*4, co=lane&15;
#pragma unroll
  for(int m=0;m<4;++m)
#pragma unroll
    for(int n=0;n<4;++n)
#pragma unroll
      for(int j=0;j<4;++j){
        const int r=bm+wr+m*16+ro4+j, c=bn+wc+n*16+co;
        if constexpr (MODE==0)      outb[(size_t)r*ncols+c]=f2bf(acc[m][n][j]+bias[c]);
        else if constexpr (MODE==1) outf[(size_t)r*ncols+c]=acc[m][n][j]+bias[c];
        else if constexpr (MODE==2){ if (c<ncols) outf[(size_t)r*ncols+c]=acc[m][n][j]+bias[c]; }
        else                        outf[((size_t)kz*128+r)*ncols+c]=acc[m][n][j];
      }
}

// ---------------------------------------------------------------------------
extern "C" void kernel_launch(void* const* d_in, const int* in_sizes, int n_in,
                              void* d_out, int out_size, void* d_ws, size_t ws_size,
                              hipStream_t stream) {
  const float* feats   =(const float*)d_in[0];
  const int*   captions=(const int*)  d_in[1];
  const float* embW    =(const float*)d_in[2];
  const float* Wf_w    =(const float*)d_in[3];
  const float* Wf_b    =(const float*)d_in[4];
  const float* Wh_w    =(const float*)d_in[5];
  const float* Wh_b    =(const float*)d_in[6];
  const float* v_w     =(const float*)d_in[7];
  const float* v_b     =(const float*)d_in[8];
  const float* W_ih    =(const float*)d_in[9];
  const float* W_hh    =(const float*)d_in[10];
  const float* b_ih    =(const float*)d_in[11];
  const float* b_hh    =(const float*)d_in[12];
  const float* init_w  =(const float*)d_in[13];
  const float* init_b  =(const float*)d_in[14];
  const float* initc_w =(const float*)d_in[15];
  const float* initc_b =(const float*)d_in[16];
  const float* out_w   =(const float*)d_in[17];
  const float* out_b   =(const float*)d_in[18];
  float* out=(float*)d_out;
  char* ws=(char*)d_ws;

  u16*   feats_bf =(u16*)  (ws+0);
  u16*   fproj    =(u16*)  (ws+25690112);
  u16*   outw_bf  =(u16*)  (ws+51380224);
  u16*   Wc       =(u16*)  (ws+82182144);
  u16*   WihE     =(u16*)  (ws+86376448);
  u16*   Whw_bf   =(u16*)  (ws+88473600);
  u16*   Wf_bf    =(u16*)  (ws+88997888);
  u16*   embx     =(u16*)  (ws+89522176);
  u16*   h_all    =(u16*)  (ws+92143616);
  u16*   xs0      =(u16*)  (ws+94765056);
  float* gemb     =(float*)(ws+95289344);
  float* cbuf     =(float*)(ws+116260864);
  float* bias_comb=(float*)(ws+116785152);
  float* gpart    =(float*)(ws+116793344);  // 4 x 128 x 2048 f32 = 4 MB

  setup_cast<<<4096,256,0,stream>>>(feats,captions,embW,Wf_w,Wh_w,W_ih,W_hh,b_ih,b_hh,out_w,
                                    feats_bf,outw_bf,Wc,WihE,embx,Whw_bf,Wf_bf,bias_comb);
  prep<<<128,256,0,stream>>>(feats,init_w,init_b,initc_w,initc_b,xs0,cbuf);
  // fproj = feats_bf @ Wf^T + Wf_b  (25088 x 512, K=512) -> bf16
  gemm_bt<0><<<dim3(4,196),256,0,stream>>>(feats_bf,512,Wf_bf,512,512,
      Wf_b,nullptr,fproj,512);
  // gemb = embx @ WihE^T + (b_ih+b_hh)  (2560 x 2048, K=512) -> f32
  gemm_bt<1><<<dim3(16,20),256,0,stream>>>(embx,512,WihE,512,512,
      bias_comb,gemb,nullptr,2048);

  for(int t=0;t<20;++t){
    attn_step<<<128,1024,0,stream>>>(fproj,feats_bf,xs0,Whw_bf,Wh_b,v_w,v_b,
                                     gemb,gpart,cbuf,h_all,t);
    // gates partials: xs(128x1024) @ Wc^T(2048x1024), K-split 4x256 -> gpart
    // (r7/r10-proven path)
    gemm_bt<4><<<dim3(16,4),256,0,stream>>>(xs0,1024,Wc,1024,256,
        nullptr,gpart,nullptr,2048);
  }
  lstm_fin<<<128,512,0,stream>>>(gemb,gpart,cbuf,h_all);
  // logits = h_all @ out_w^T + out_b, transposed grid for out_w L2 reuse
  gemm_bt<2><<<dim3(20,235),256,0,stream>>>(h_all,512,outw_bf,512,512,
      out_b,out,nullptr,30000);
}

// Round 13
// 1151.708 us; speedup vs baseline: 6.3115x; 1.0173x over previous
//
#include <hip/hip_runtime.h>
#include <stdint.h>
#include <stddef.h>

typedef unsigned short u16;
typedef __attribute__((ext_vector_type(8))) short short8;
typedef __attribute__((ext_vector_type(4))) float f32x4;

#define DEV static __device__ __forceinline__

DEV float bf2f(u16 u){ return __uint_as_float(((unsigned)u)<<16); }
DEV u16 f2bf(float f){ unsigned x=__float_as_uint(f); return (u16)((x + 0x7fffu + ((x>>16)&1u))>>16); }

DEV float wsum(float v){
#pragma unroll
  for(int o=32;o;o>>=1) v += __shfl_xor(v,o);
  return v;
}
DEV float wmax(float v){
#pragma unroll
  for(int o=32;o;o>>=1) v = fmaxf(v,__shfl_xor(v,o));
  return v;
}
DEV float sigm(float x){ return __fdividef(1.f, 1.f+__expf(-x)); }
DEV float tanhx(float x){ float e=__expf(-2.f*fabsf(x)); float t=__fdividef(1.f-e,1.f+e); return x<0.f?-t:t; }

DEV f32x4 mfma16(short8 a, short8 b, f32x4 c){
  asm("v_mfma_f32_16x16x32_bf16 %0, %1, %2, %0" : "+v"(c) : "v"(a), "v"(b));
  return c;
}
DEV void gll16(const void* g, void* l){
  __builtin_amdgcn_global_load_lds((const __attribute__((address_space(1))) void*)g,
                                   (__attribute__((address_space(3))) void*)l, 16, 0, 0);
}

DEV void pack8(u16* dst, const float* src){
  const float4 a=*(const float4*)(src);
  const float4 b=*(const float4*)(src+4);
  short8 o;
  o[0]=(short)f2bf(a.x); o[1]=(short)f2bf(a.y); o[2]=(short)f2bf(a.z); o[3]=(short)f2bf(a.w);
  o[4]=(short)f2bf(b.x); o[5]=(short)f2bf(b.y); o[6]=(short)f2bf(b.z); o[7]=(short)f2bf(b.w);
  *(short8*)dst=o;
}
DEV void zero8(u16* dst){
  short8 z;
#pragma unroll
  for(int e=0;e<8;++e) z[e]=0;
  *(short8*)dst=z;
}

// ---------------------------------------------------------------------------
// setup: fp32->bf16 casts, weight reorders, embedding gather, combined bias.
// Gate rows unit-major: new row r <-> orig row o=((r&3)<<9)+(r>>2).
// ---------------------------------------------------------------------------
__global__ __launch_bounds__(256) void setup_cast(
  const float* __restrict__ feats, const int* __restrict__ captions,
  const float* __restrict__ embW, const float* __restrict__ Wf_w,
  const float* __restrict__ Wh_w, const float* __restrict__ W_ih,
  const float* __restrict__ W_hh, const float* __restrict__ b_ih,
  const float* __restrict__ b_hh, const float* __restrict__ out_w,
  u16* __restrict__ feats_bf, u16* __restrict__ outw_bf, u16* __restrict__ Wc,
  u16* __restrict__ WihE, u16* __restrict__ embx, u16* __restrict__ Whw_bf,
  u16* __restrict__ Wf_bf, float* __restrict__ bias_comb)
{
  const long long o0=12845056LL,o1=28246016LL,o2=30343168LL,o3=31391744LL,
                  o4=32702464LL,o5=32964608LL,o6=33226752LL,total=33228800LL;
  for (long long i8=((long long)blockIdx.x*256+threadIdx.x)*8; i8<total;
       i8+=(long long)gridDim.x*256*8){
    const long long i=i8;
    if (i<o0){ pack8(feats_bf+i, feats+i); }
    else if (i<o1){ const long long j=i-o0; const int r=(int)(j>>9);
      if (r<30000) pack8(outw_bf+j, out_w+j); else zero8(outw_bf+j); }
    else if (i<o2){ const long long j=i-o1; const int r=(int)(j>>10), k=(int)(j&1023);
      const int o=((r&3)<<9)+(r>>2);
      const float* s=(k<512)? (W_ih+(size_t)o*1024+512+k) : (W_hh+(size_t)o*512+(k-512));
      pack8(Wc+j, s); }
    else if (i<o3){ const long long j=i-o2; const int r=(int)(j>>9), k=(int)(j&511);
      const int o=((r&3)<<9)+(r>>2);
      pack8(WihE+j, W_ih+(size_t)o*1024+k); }
    else if (i<o4){ const long long j=i-o3; const int m=(int)(j>>9), e=(int)(j&511);
      const int b=m/20, tt=m-b*20; const int idx=captions[b*21+tt];
      if (idx) pack8(embx+j, embW+(size_t)idx*512+e); else zero8(embx+j); }
    else if (i<o5){ const long long j=i-o4; pack8(Whw_bf+j, Wh_w+j); }
    else if (i<o6){ const long long j=i-o5; pack8(Wf_bf+j, Wf_w+j); }
    else { const long long j=i-o6;
      for(int e=0;e<8;++e){ const int r=(int)(j+e); const int o=((r&3)<<9)+(r>>2);
        bias_comb[r]=b_ih[o]+b_hh[o]; } }
  }
}

// ---------------------------------------------------------------------------
// prep: gfeat = mean(feats), h0/c0. h0 (bf16) -> xs h-slot, c0 (fp32) -> cbuf.
// ---------------------------------------------------------------------------
__global__ __launch_bounds__(256) void prep(
  const float* __restrict__ feats, const float* __restrict__ init_w,
  const float* __restrict__ init_b, const float* __restrict__ initc_w,
  const float* __restrict__ initc_b, u16* __restrict__ xs0, float* __restrict__ cbuf)
{
  const int b=blockIdx.x, tid=threadIdx.x, lane=tid&63, w=tid>>6;
  __shared__ float gf[512];
  const float* fb=feats+(size_t)b*196*512;
  float a0=0.f,a1=0.f;
  for(int n=0;n<196;++n){ a0+=fb[(size_t)n*512+tid]; a1+=fb[(size_t)n*512+tid+256]; }
  gf[tid]=a0*(1.f/196.f); gf[tid+256]=a1*(1.f/196.f);
  __syncthreads();
  const int kb=lane*8;
  float g8[8];
#pragma unroll
  for(int e=0;e<8;++e) g8[e]=gf[kb+e];
  for(int j=w*128;j<w*128+128;++j){
    const float* r1=init_w+(size_t)j*512+kb;
    const float* r2=initc_w+(size_t)j*512+kb;
    float s1=0.f,s2=0.f;
#pragma unroll
    for(int e=0;e<8;++e){ s1+=g8[e]*r1[e]; s2+=g8[e]*r2[e]; }
    s1=wsum(s1); s2=wsum(s2);
    if(lane==(j&63)){ xs0[b*1024+512+j]=f2bf(s1+init_b[j]); cbuf[b*512+j]=s2+initc_b[j]; }
  }
}

// ---------------------------------------------------------------------------
// attn_step: 128 blocks x 1024 threads (16 waves), r12 structure (4-row
// batched hproj/scores/ctx). Prologue (t>0): LSTM for step t-1, now summing
// EIGHT gpart K-slices (r8-proven numerics).
// ---------------------------------------------------------------------------
__global__ __launch_bounds__(1024) void attn_step(
  const u16* __restrict__ fproj, const u16* __restrict__ feats_bf,
  u16* __restrict__ xs, const u16* __restrict__ Whw,
  const float* __restrict__ Whb, const float* __restrict__ vw,
  const float* __restrict__ vb, const float* __restrict__ gemb,
  const float* __restrict__ gpart, float* __restrict__ cbuf,
  u16* __restrict__ h_all, int t)
{
  const int b=blockIdx.x, tid=threadIdx.x, lane=tid&63, w=tid>>6;
  __shared__ float part[16][512];
  __shared__ float hsf[512], hp[512], sc[208], red[16];
  if (t>0){
    if (tid<512){
      const int u=tid;
      float4 g4=*(const float4*)&gemb[((size_t)b*20+(t-1))*2048+u*4];
#pragma unroll
      for(int kz=0;kz<8;++kz){
        const float4 p=*(const float4*)&gpart[((size_t)kz*128+b)*2048+u*4];
        g4.x+=p.x; g4.y+=p.y; g4.z+=p.z; g4.w+=p.w;
      }
      const float cn=sigm(g4.y)*cbuf[b*512+u]+sigm(g4.x)*tanhx(g4.z);
      const float hn=sigm(g4.w)*tanhx(cn);
      cbuf[b*512+u]=cn;
      const u16 hb=f2bf(hn);
      xs[b*1024+512+u]=hb;
      h_all[((size_t)b*20+(t-1))*512+u]=hb;
      hsf[u]=bf2f(hb);
    }
  } else {
    if (tid<512) hsf[tid]=bf2f(xs[b*1024+512+tid]);
  }
  __syncthreads();
  const int kb=lane*8;
  float h8[8];
#pragma unroll
  for(int e=0;e<8;++e) h8[e]=hsf[kb+e];
  // hproj: wave w owns rows [32w, 32w+32), 4 rows per iteration
#pragma unroll
  for(int jj=0;jj<32;jj+=4){
    const int j=w*32+jj;
    short8 w0=*(const short8*)(Whw+(size_t)j*512+kb);
    short8 w1=*(const short8*)(Whw+(size_t)(j+1)*512+kb);
    short8 w2=*(const short8*)(Whw+(size_t)(j+2)*512+kb);
    short8 w3=*(const short8*)(Whw+(size_t)(j+3)*512+kb);
    float s0=0.f,s1=0.f,s2=0.f,s3=0.f;
#pragma unroll
    for(int e=0;e<8;++e){
      const float he=h8[e];
      s0+=he*bf2f((u16)w0[e]);
      s1+=he*bf2f((u16)w1[e]);
      s2+=he*bf2f((u16)w2[e]);
      s3+=he*bf2f((u16)w3[e]);
    }
    s0=wsum(s0); s1=wsum(s1); s2=wsum(s2); s3=wsum(s3);
    if(lane==0){ hp[j]=s0+Whb[j]; hp[j+1]=s1+Whb[j+1];
                 hp[j+2]=s2+Whb[j+2]; hp[j+3]=s3+Whb[j+3]; }
  }
  __syncthreads();
  // scores: v·tanh(f+p) = v - 2v/(exp(2(f+p))+1); 4-row batching
  float p2[8], vm2[8];
  float sv=0.f;
#pragma unroll
  for(int e=0;e<8;++e){
    const float p=hp[kb+e], v=vw[kb+e];
    p2[e]=2.f*p; vm2[e]=-2.f*v; sv+=v;
  }
  const float vb0=vb[0];
#pragma unroll
  for(int i=0;i<12;i+=4){
    const int n0=w+16*i;
    short8 f0=*(const short8*)(fproj+((size_t)b*196+n0   )*512+kb);
    short8 f1=*(const short8*)(fproj+((size_t)b*196+n0+16)*512+kb);
    short8 f2=*(const short8*)(fproj+((size_t)b*196+n0+32)*512+kb);
    short8 f3=*(const short8*)(fproj+((size_t)b*196+n0+48)*512+kb);
    float s0=sv,s1=sv,s2=sv,s3=sv;
#pragma unroll
    for(int e=0;e<8;++e){
      s0+=__fdividef(vm2[e],__expf(fmaf(bf2f((u16)f0[e]),2.f,p2[e]))+1.f);
      s1+=__fdividef(vm2[e],__expf(fmaf(bf2f((u16)f1[e]),2.f,p2[e]))+1.f);
      s2+=__fdividef(vm2[e],__expf(fmaf(bf2f((u16)f2[e]),2.f,p2[e]))+1.f);
      s3+=__fdividef(vm2[e],__expf(fmaf(bf2f((u16)f3[e]),2.f,p2[e]))+1.f);
    }
    s0=wsum(s0); s1=wsum(s1); s2=wsum(s2); s3=wsum(s3);
    if(lane==0){
      sc[n0   ]=s0+vb0;
      sc[n0+16]=s1+vb0;
      sc[n0+32]=s2+vb0;
      sc[n0+48]=s3+vb0;
    }
  }
  {
    const int n=w+192;
    if (n<196){
      short8 f0=*(const short8*)(fproj+((size_t)b*196+n)*512+kb);
      float s0=sv;
#pragma unroll
      for(int e=0;e<8;++e)
        s0+=__fdividef(vm2[e],__expf(fmaf(bf2f((u16)f0[e]),2.f,p2[e]))+1.f);
      s0=wsum(s0);
      if(lane==0) sc[n]=s0+vb0;
    }
  }
  __syncthreads();
  // softmax over 196
  float xv=(tid<196)? sc[tid] : -3.0e38f;
  float mx=wmax(xv);
  if(lane==0) red[w]=mx;
  __syncthreads();
  float mm=red[0];
#pragma unroll
  for(int i=1;i<16;++i) mm=fmaxf(mm,red[i]);
  float pv=(tid<196)? __expf(xv-mm) : 0.f;
  float ps=wsum(pv);
  __syncthreads();
  if(lane==0) red[w]=ps;
  __syncthreads();
  float tot=red[0];
#pragma unroll
  for(int i=1;i<16;++i) tot+=red[i];
  if(tid<196) sc[tid]=__fdividef(pv,tot);
  __syncthreads();
  // ctx partials: wave w accumulates rows w+16i, 4-row batching
  float a8[8];
#pragma unroll
  for(int e=0;e<8;++e) a8[e]=0.f;
#pragma unroll
  for(int i=0;i<12;i+=4){
    const int n0=w+16*i;
    short8 v0=*(const short8*)(feats_bf+((size_t)b*196+n0   )*512+kb);
    short8 v1=*(const short8*)(feats_bf+((size_t)b*196+n0+16)*512+kb);
    short8 v2=*(const short8*)(feats_bf+((size_t)b*196+n0+32)*512+kb);
    short8 v3=*(const short8*)(feats_bf+((size_t)b*196+n0+48)*512+kb);
    const float wn0=sc[n0], wn1=sc[n0+16], wn2=sc[n0+32], wn3=sc[n0+48];
#pragma unroll
    for(int e=0;e<8;++e)
      a8[e]+=wn0*bf2f((u16)v0[e])+wn1*bf2f((u16)v1[e])
            +wn2*bf2f((u16)v2[e])+wn3*bf2f((u16)v3[e]);
  }
  {
    const int n=w+192;
    if (n<196){
      short8 v0=*(const short8*)(feats_bf+((size_t)b*196+n)*512+kb);
      const float wn=sc[n];
#pragma unroll
      for(int e=0;e<8;++e) a8[e]+=wn*bf2f((u16)v0[e]);
    }
  }
  *(float4*)&part[w][kb]  =*(float4*)&a8[0];
  *(float4*)&part[w][kb+4]=*(float4*)&a8[4];
  __syncthreads();
  if (tid<512){
    float s=0.f;
#pragma unroll
    for(int i=0;i<16;++i) s+=part[i][tid];
    xs[b*1024+tid]=f2bf(s);
  }
}

// ---------------------------------------------------------------------------
// lstm_fin: LSTM for the final step (t=19) — h_all only. 8 gpart slices.
// ---------------------------------------------------------------------------
__global__ __launch_bounds__(512) void lstm_fin(
  const float* __restrict__ gemb, const float* __restrict__ gpart,
  const float* __restrict__ cbuf, u16* __restrict__ h_all)
{
  const int b=blockIdx.x, u=threadIdx.x;
  float4 g4=*(const float4*)&gemb[((size_t)b*20+19)*2048+u*4];
#pragma unroll
  for(int kz=0;kz<8;++kz){
    const float4 p=*(const float4*)&gpart[((size_t)kz*128+b)*2048+u*4];
    g4.x+=p.x; g4.y+=p.y; g4.z+=p.z; g4.w+=p.w;
  }
  const float cn=sigm(g4.y)*cbuf[b*512+u]+sigm(g4.x)*tanhx(g4.z);
  const float hn=sigm(g4.w)*tanhx(cn);
  h_all[((size_t)b*20+19)*512+u]=f2bf(hn);
}

// ---------------------------------------------------------------------------
// gemm_bt: C[M,N] = A[M,K] * B[N,K]^T, 128x128 tile, m97 structure.
// MODE 0: bf16 out + bias   MODE 1: f32 out + bias
// MODE 2: f32 + col guard, TRANSPOSED GRID (x = row tile, y = col tile) so
//         consecutive blocks share a B column-tile -> L2 reuse of out_w.
// MODE 4: K-split partial (blockIdx.y = kz, base += kz*K, bm=0) — proven
//         r7/r10 path, now with 8 slices of K=128 (4 chunk-iterations).
// ---------------------------------------------------------------------------
template<int MODE>
__global__ __launch_bounds__(256) void gemm_bt(
  const u16* __restrict__ A, int lda, const u16* __restrict__ Bw, int ldb, int K,
  const float* __restrict__ bias, float* __restrict__ outf, u16* __restrict__ outb,
  int ncols)
{
  const int bm=(MODE==4)? 0 : ((MODE==2)? blockIdx.x*128 : blockIdx.y*128);
  const int bn=(MODE==2)? blockIdx.y*128 : blockIdx.x*128;
  const int kz=(MODE==4)? blockIdx.y : 0;
  const u16* __restrict__ Ap=A +(size_t)kz*K;
  const u16* __restrict__ Bp=Bw+(size_t)kz*K;
  const int tid=threadIdx.x, lane=tid&63, wave=tid>>6;
  const int wr=(wave>>1)*64, wc=(wave&1)*64;
  __shared__ u16 As[128*32], Bs[128*32];
  f32x4 acc[4][4]={};
  const int srow=tid>>2, scol=(tid&3)*8;
  for(int k0=0;k0<K;k0+=32){
    gll16(Ap+(size_t)(bm+srow)*lda    +k0+scol, As+tid*8);
    gll16(Ap+(size_t)(bm+64+srow)*lda +k0+scol, As+2048+tid*8);
    gll16(Bp+(size_t)(bn+srow)*ldb    +k0+scol, Bs+tid*8);
    gll16(Bp+(size_t)(bn+64+srow)*ldb +k0+scol, Bs+2048+tid*8);
    __syncthreads();
    short8 af[4], bfr[4];
    const int ro=lane&15, ko=(lane>>4)*8;
#pragma unroll
    for(int m=0;m<4;++m) af[m]=*(const short8*)(As+(wr+m*16+ro)*32+ko);
#pragma unroll
    for(int n=0;n<4;++n) bfr[n]=*(const short8*)(Bs+(wc+n*16+ro)*32+ko);
#pragma unroll
    for(int m=0;m<4;++m)
#pragma unroll
      for(int n=0;n<4;++n) acc[m][n]=mfma16(af[m],bfr[n],acc[m][n]);
    __syncthreads();
  }
  asm volatile("s_nop 7\ns_nop 7\ns_nop 7");  // MFMA->VALU hazard guard
  const int ro4=(lane>>4)*4, co=lane&15;
#pragma unroll
  for(int m=0;m<4;++m)
#pragma unroll
    for(int n=0;n<4;++n)
#pragma unroll
      for(int j=0;j<4;++j){
        const int r=bm+wr+m*16+ro4+j, c=bn+wc+n*16+co;
        if constexpr (MODE==0)      outb[(size_t)r*ncols+c]=f2bf(acc[m][n][j]+bias[c]);
        else if constexpr (MODE==1) outf[(size_t)r*ncols+c]=acc[m][n][j]+bias[c];
        else if constexpr (MODE==2){ if (c<ncols) outf[(size_t)r*ncols+c]=acc[m][n][j]+bias[c]; }
        else                        outf[((size_t)kz*128+r)*ncols+c]=acc[m][n][j];
      }
}

// ---------------------------------------------------------------------------
extern "C" void kernel_launch(void* const* d_in, const int* in_sizes, int n_in,
                              void* d_out, int out_size, void* d_ws, size_t ws_size,
                              hipStream_t stream) {
  const float* feats   =(const float*)d_in[0];
  const int*   captions=(const int*)  d_in[1];
  const float* embW    =(const float*)d_in[2];
  const float* Wf_w    =(const float*)d_in[3];
  const float* Wf_b    =(const float*)d_in[4];
  const float* Wh_w    =(const float*)d_in[5];
  const float* Wh_b    =(const float*)d_in[6];
  const float* v_w     =(const float*)d_in[7];
  const float* v_b     =(const float*)d_in[8];
  const float* W_ih    =(const float*)d_in[9];
  const float* W_hh    =(const float*)d_in[10];
  const float* b_ih    =(const float*)d_in[11];
  const float* b_hh    =(const float*)d_in[12];
  const float* init_w  =(const float*)d_in[13];
  const float* init_b  =(const float*)d_in[14];
  const float* initc_w =(const float*)d_in[15];
  const float* initc_b =(const float*)d_in[16];
  const float* out_w   =(const float*)d_in[17];
  const float* out_b   =(const float*)d_in[18];
  float* out=(float*)d_out;
  char* ws=(char*)d_ws;

  u16*   feats_bf =(u16*)  (ws+0);
  u16*   fproj    =(u16*)  (ws+25690112);
  u16*   outw_bf  =(u16*)  (ws+51380224);
  u16*   Wc       =(u16*)  (ws+82182144);
  u16*   WihE     =(u16*)  (ws+86376448);
  u16*   Whw_bf   =(u16*)  (ws+88473600);
  u16*   Wf_bf    =(u16*)  (ws+88997888);
  u16*   embx     =(u16*)  (ws+89522176);
  u16*   h_all    =(u16*)  (ws+92143616);
  u16*   xs0      =(u16*)  (ws+94765056);
  float* gemb     =(float*)(ws+95289344);
  float* cbuf     =(float*)(ws+116260864);
  float* bias_comb=(float*)(ws+116785152);
  float* gpart    =(float*)(ws+116793344);  // 8 x 128 x 2048 f32 = 8 MB

  setup_cast<<<4096,256,0,stream>>>(feats,captions,embW,Wf_w,Wh_w,W_ih,W_hh,b_ih,b_hh,out_w,
                                    feats_bf,outw_bf,Wc,WihE,embx,Whw_bf,Wf_bf,bias_comb);
  prep<<<128,256,0,stream>>>(feats,init_w,init_b,initc_w,initc_b,xs0,cbuf);
  // fproj = feats_bf @ Wf^T + Wf_b  (25088 x 512, K=512) -> bf16
  gemm_bt<0><<<dim3(4,196),256,0,stream>>>(feats_bf,512,Wf_bf,512,512,
      Wf_b,nullptr,fproj,512);
  // gemb = embx @ WihE^T + (b_ih+b_hh)  (2560 x 2048, K=512) -> f32
  gemm_bt<1><<<dim3(16,20),256,0,stream>>>(embx,512,WihE,512,512,
      bias_comb,gemb,nullptr,2048);

  for(int t=0;t<20;++t){
    attn_step<<<128,1024,0,stream>>>(fproj,feats_bf,xs0,Whw_bf,Wh_b,v_w,v_b,
                                     gemb,gpart,cbuf,h_all,t);
    // gates partials: xs(128x1024) @ Wc^T(2048x1024), K-split 8x128 -> gpart
    gemm_bt<4><<<dim3(16,8),256,0,stream>>>(xs0,1024,Wc,1024,128,
        nullptr,gpart,nullptr,2048);
  }
  lstm_fin<<<128,512,0,stream>>>(gemb,gpart,cbuf,h_all);
  // logits = h_all @ out_w^T + out_b, transposed grid for out_w L2 reuse
  gemm_bt<2><<<dim3(20,235),256,0,stream>>>(h_all,512,outw_bf,512,512,
      out_b,out,nullptr,30000);
}

// Round 14
// 1141.283 us; speedup vs baseline: 6.3692x; 1.0091x over previous
//
#include <hip/hip_runtime.h>
#include <stdint.h>
#include <stddef.h>

typedef unsigned short u16;
typedef __attribute__((ext_vector_type(8))) short short8;
typedef __attribute__((ext_vector_type(4))) float f32x4;

#define DEV static __device__ __forceinline__

DEV float bf2f(u16 u){ return __uint_as_float(((unsigned)u)<<16); }
DEV u16 f2bf(float f){ unsigned x=__float_as_uint(f); return (u16)((x + 0x7fffu + ((x>>16)&1u))>>16); }

DEV float wsum(float v){
#pragma unroll
  for(int o=32;o;o>>=1) v += __shfl_xor(v,o);
  return v;
}
DEV float wmax(float v){
#pragma unroll
  for(int o=32;o;o>>=1) v = fmaxf(v,__shfl_xor(v,o));
  return v;
}
DEV float sigm(float x){ return __fdividef(1.f, 1.f+__expf(-x)); }
DEV float tanhx(float x){ float e=__expf(-2.f*fabsf(x)); float t=__fdividef(1.f-e,1.f+e); return x<0.f?-t:t; }

DEV f32x4 mfma16(short8 a, short8 b, f32x4 c){
  asm("v_mfma_f32_16x16x32_bf16 %0, %1, %2, %0" : "+v"(c) : "v"(a), "v"(b));
  return c;
}
DEV void gll16(const void* g, void* l){
  __builtin_amdgcn_global_load_lds((const __attribute__((address_space(1))) void*)g,
                                   (__attribute__((address_space(3))) void*)l, 16, 0, 0);
}

DEV void pack8(u16* dst, const float* src){
  const float4 a=*(const float4*)(src);
  const float4 b=*(const float4*)(src+4);
  short8 o;
  o[0]=(short)f2bf(a.x); o[1]=(short)f2bf(a.y); o[2]=(short)f2bf(a.z); o[3]=(short)f2bf(a.w);
  o[4]=(short)f2bf(b.x); o[5]=(short)f2bf(b.y); o[6]=(short)f2bf(b.z); o[7]=(short)f2bf(b.w);
  *(short8*)dst=o;
}
DEV void zero8(u16* dst){
  short8 z;
#pragma unroll
  for(int e=0;e<8;++e) z[e]=0;
  *(short8*)dst=z;
}

// ---------------------------------------------------------------------------
// setup: fp32->bf16 casts, weight reorders, embedding gather, combined bias.
// Gate rows unit-major: new row r <-> orig row o=((r&3)<<9)+(r>>2).
// ---------------------------------------------------------------------------
__global__ __launch_bounds__(256) void setup_cast(
  const float* __restrict__ feats, const int* __restrict__ captions,
  const float* __restrict__ embW, const float* __restrict__ Wf_w,
  const float* __restrict__ Wh_w, const float* __restrict__ W_ih,
  const float* __restrict__ W_hh, const float* __restrict__ b_ih,
  const float* __restrict__ b_hh, const float* __restrict__ out_w,
  u16* __restrict__ feats_bf, u16* __restrict__ outw_bf, u16* __restrict__ Wc,
  u16* __restrict__ WihE, u16* __restrict__ embx, u16* __restrict__ Whw_bf,
  u16* __restrict__ Wf_bf, float* __restrict__ bias_comb)
{
  const long long o0=12845056LL,o1=28246016LL,o2=30343168LL,o3=31391744LL,
                  o4=32702464LL,o5=32964608LL,o6=33226752LL,total=33228800LL;
  for (long long i8=((long long)blockIdx.x*256+threadIdx.x)*8; i8<total;
       i8+=(long long)gridDim.x*256*8){
    const long long i=i8;
    if (i<o0){ pack8(feats_bf+i, feats+i); }
    else if (i<o1){ const long long j=i-o0; const int r=(int)(j>>9);
      if (r<30000) pack8(outw_bf+j, out_w+j); else zero8(outw_bf+j); }
    else if (i<o2){ const long long j=i-o1; const int r=(int)(j>>10), k=(int)(j&1023);
      const int o=((r&3)<<9)+(r>>2);
      const float* s=(k<512)? (W_ih+(size_t)o*1024+512+k) : (W_hh+(size_t)o*512+(k-512));
      pack8(Wc+j, s); }
    else if (i<o3){ const long long j=i-o2; const int r=(int)(j>>9), k=(int)(j&511);
      const int o=((r&3)<<9)+(r>>2);
      pack8(WihE+j, W_ih+(size_t)o*1024+k); }
    else if (i<o4){ const long long j=i-o3; const int m=(int)(j>>9), e=(int)(j&511);
      const int b=m/20, tt=m-b*20; const int idx=captions[b*21+tt];
      if (idx) pack8(embx+j, embW+(size_t)idx*512+e); else zero8(embx+j); }
    else if (i<o5){ const long long j=i-o4; pack8(Whw_bf+j, Wh_w+j); }
    else if (i<o6){ const long long j=i-o5; pack8(Wf_bf+j, Wf_w+j); }
    else { const long long j=i-o6;
      for(int e=0;e<8;++e){ const int r=(int)(j+e); const int o=((r&3)<<9)+(r>>2);
        bias_comb[r]=b_ih[o]+b_hh[o]; } }
  }
}

// ---------------------------------------------------------------------------
// prep: gfeat = mean(feats), h0/c0. h0 (bf16) -> xs h-slot, c0 (fp32) -> cbuf.
// ---------------------------------------------------------------------------
__global__ __launch_bounds__(256) void prep(
  const float* __restrict__ feats, const float* __restrict__ init_w,
  const float* __restrict__ init_b, const float* __restrict__ initc_w,
  const float* __restrict__ initc_b, u16* __restrict__ xs0, float* __restrict__ cbuf)
{
  const int b=blockIdx.x, tid=threadIdx.x, lane=tid&63, w=tid>>6;
  __shared__ float gf[512];
  const float* fb=feats+(size_t)b*196*512;
  float a0=0.f,a1=0.f;
  for(int n=0;n<196;++n){ a0+=fb[(size_t)n*512+tid]; a1+=fb[(size_t)n*512+tid+256]; }
  gf[tid]=a0*(1.f/196.f); gf[tid+256]=a1*(1.f/196.f);
  __syncthreads();
  const int kb=lane*8;
  float g8[8];
#pragma unroll
  for(int e=0;e<8;++e) g8[e]=gf[kb+e];
  for(int j=w*128;j<w*128+128;++j){
    const float* r1=init_w+(size_t)j*512+kb;
    const float* r2=initc_w+(size_t)j*512+kb;
    float s1=0.f,s2=0.f;
#pragma unroll
    for(int e=0;e<8;++e){ s1+=g8[e]*r1[e]; s2+=g8[e]*r2[e]; }
    s1=wsum(s1); s2=wsum(s2);
    if(lane==(j&63)){ xs0[b*1024+512+j]=f2bf(s1+init_b[j]); cbuf[b*512+j]=s2+initc_b[j]; }
  }
}

// ---------------------------------------------------------------------------
// attn_step: 128 blocks x 1024 threads (16 waves). r13 structure with DEEPER
// load batching: hproj 8-row, scores 6-row, ctx 6-row (more loads in flight).
// Prologue (t>0): LSTM for step t-1 (8 gpart K-slices).
// ---------------------------------------------------------------------------
__global__ __launch_bounds__(1024) void attn_step(
  const u16* __restrict__ fproj, const u16* __restrict__ feats_bf,
  u16* __restrict__ xs, const u16* __restrict__ Whw,
  const float* __restrict__ Whb, const float* __restrict__ vw,
  const float* __restrict__ vb, const float* __restrict__ gemb,
  const float* __restrict__ gpart, float* __restrict__ cbuf,
  u16* __restrict__ h_all, int t)
{
  const int b=blockIdx.x, tid=threadIdx.x, lane=tid&63, w=tid>>6;
  __shared__ float part[16][512];
  __shared__ float hsf[512], hp[512], sc[208], red[16];
  if (t>0){
    if (tid<512){
      const int u=tid;
      float4 g4=*(const float4*)&gemb[((size_t)b*20+(t-1))*2048+u*4];
#pragma unroll
      for(int kz=0;kz<8;++kz){
        const float4 p=*(const float4*)&gpart[((size_t)kz*128+b)*2048+u*4];
        g4.x+=p.x; g4.y+=p.y; g4.z+=p.z; g4.w+=p.w;
      }
      const float cn=sigm(g4.y)*cbuf[b*512+u]+sigm(g4.x)*tanhx(g4.z);
      const float hn=sigm(g4.w)*tanhx(cn);
      cbuf[b*512+u]=cn;
      const u16 hb=f2bf(hn);
      xs[b*1024+512+u]=hb;
      h_all[((size_t)b*20+(t-1))*512+u]=hb;
      hsf[u]=bf2f(hb);
    }
  } else {
    if (tid<512) hsf[tid]=bf2f(xs[b*1024+512+tid]);
  }
  __syncthreads();
  const int kb=lane*8;
  float h8[8];
#pragma unroll
  for(int e=0;e<8;++e) h8[e]=hsf[kb+e];
  // hproj: wave w owns rows [32w, 32w+32), 8 rows per iteration
#pragma unroll
  for(int jj=0;jj<32;jj+=8){
    const int j=w*32+jj;
    short8 wv[8];
#pragma unroll
    for(int r=0;r<8;++r) wv[r]=*(const short8*)(Whw+(size_t)(j+r)*512+kb);
    float s[8];
#pragma unroll
    for(int r=0;r<8;++r) s[r]=0.f;
#pragma unroll
    for(int e=0;e<8;++e){
      const float he=h8[e];
#pragma unroll
      for(int r=0;r<8;++r) s[r]+=he*bf2f((u16)wv[r][e]);
    }
#pragma unroll
    for(int r=0;r<8;++r) s[r]=wsum(s[r]);
    if(lane==0){
#pragma unroll
      for(int r=0;r<8;++r) hp[j+r]=s[r]+Whb[j+r];
    }
  }
  __syncthreads();
  // scores: v·tanh(f+p) = v - 2v/(exp(2(f+p))+1); 6-row batching
  float p2[8], vm2[8];
  float sv=0.f;
#pragma unroll
  for(int e=0;e<8;++e){
    const float p=hp[kb+e], v=vw[kb+e];
    p2[e]=2.f*p; vm2[e]=-2.f*v; sv+=v;
  }
  const float vb0=vb[0];
#pragma unroll
  for(int i=0;i<12;i+=6){
    const int n0=w+16*i;
    short8 f[6];
#pragma unroll
    for(int r=0;r<6;++r) f[r]=*(const short8*)(fproj+((size_t)b*196+n0+16*r)*512+kb);
    float s[6];
#pragma unroll
    for(int r=0;r<6;++r) s[r]=sv;
#pragma unroll
    for(int e=0;e<8;++e){
#pragma unroll
      for(int r=0;r<6;++r)
        s[r]+=__fdividef(vm2[e],__expf(fmaf(bf2f((u16)f[r][e]),2.f,p2[e]))+1.f);
    }
#pragma unroll
    for(int r=0;r<6;++r) s[r]=wsum(s[r]);
    if(lane==0){
#pragma unroll
      for(int r=0;r<6;++r) sc[n0+16*r]=s[r]+vb0;
    }
  }
  {
    const int n=w+192;
    if (n<196){
      short8 f0=*(const short8*)(fproj+((size_t)b*196+n)*512+kb);
      float s0=sv;
#pragma unroll
      for(int e=0;e<8;++e)
        s0+=__fdividef(vm2[e],__expf(fmaf(bf2f((u16)f0[e]),2.f,p2[e]))+1.f);
      s0=wsum(s0);
      if(lane==0) sc[n]=s0+vb0;
    }
  }
  __syncthreads();
  // softmax over 196
  float xv=(tid<196)? sc[tid] : -3.0e38f;
  float mx=wmax(xv);
  if(lane==0) red[w]=mx;
  __syncthreads();
  float mm=red[0];
#pragma unroll
  for(int i=1;i<16;++i) mm=fmaxf(mm,red[i]);
  float pv=(tid<196)? __expf(xv-mm) : 0.f;
  float ps=wsum(pv);
  __syncthreads();
  if(lane==0) red[w]=ps;
  __syncthreads();
  float tot=red[0];
#pragma unroll
  for(int i=1;i<16;++i) tot+=red[i];
  if(tid<196) sc[tid]=__fdividef(pv,tot);
  __syncthreads();
  // ctx partials: wave w accumulates rows w+16i, 6-row batching
  float a8[8];
#pragma unroll
  for(int e=0;e<8;++e) a8[e]=0.f;
#pragma unroll
  for(int i=0;i<12;i+=6){
    const int n0=w+16*i;
    short8 v[6];
#pragma unroll
    for(int r=0;r<6;++r) v[r]=*(const short8*)(feats_bf+((size_t)b*196+n0+16*r)*512+kb);
    float wn[6];
#pragma unroll
    for(int r=0;r<6;++r) wn[r]=sc[n0+16*r];
#pragma unroll
    for(int e=0;e<8;++e){
      float acc=a8[e];
#pragma unroll
      for(int r=0;r<6;++r) acc+=wn[r]*bf2f((u16)v[r][e]);
      a8[e]=acc;
    }
  }
  {
    const int n=w+192;
    if (n<196){
      short8 v0=*(const short8*)(feats_bf+((size_t)b*196+n)*512+kb);
      const float wn=sc[n];
#pragma unroll
      for(int e=0;e<8;++e) a8[e]+=wn*bf2f((u16)v0[e]);
    }
  }
  *(float4*)&part[w][kb]  =*(float4*)&a8[0];
  *(float4*)&part[w][kb+4]=*(float4*)&a8[4];
  __syncthreads();
  if (tid<512){
    float s=0.f;
#pragma unroll
    for(int i=0;i<16;++i) s+=part[i][tid];
    xs[b*1024+tid]=f2bf(s);
  }
}

// ---------------------------------------------------------------------------
// lstm_fin: LSTM for the final step (t=19) — h_all only. 8 gpart slices.
// ---------------------------------------------------------------------------
__global__ __launch_bounds__(512) void lstm_fin(
  const float* __restrict__ gemb, const float* __restrict__ gpart,
  const float* __restrict__ cbuf, u16* __restrict__ h_all)
{
  const int b=blockIdx.x, u=threadIdx.x;
  float4 g4=*(const float4*)&gemb[((size_t)b*20+19)*2048+u*4];
#pragma unroll
  for(int kz=0;kz<8;++kz){
    const float4 p=*(const float4*)&gpart[((size_t)kz*128+b)*2048+u*4];
    g4.x+=p.x; g4.y+=p.y; g4.z+=p.z; g4.w+=p.w;
  }
  const float cn=sigm(g4.y)*cbuf[b*512+u]+sigm(g4.x)*tanhx(g4.z);
  const float hn=sigm(g4.w)*tanhx(cn);
  h_all[((size_t)b*20+19)*512+u]=f2bf(hn);
}

// ---------------------------------------------------------------------------
// gemm_bt: C[M,N] = A[M,K] * B[N,K]^T, 128x128 tile, m97 structure.
// MODE 0: bf16 out + bias   MODE 1: f32 out + bias
// MODE 2: f32 + col guard, TRANSPOSED GRID (x = row tile, y = col tile) so
//         consecutive blocks share a B column-tile -> L2 reuse of out_w.
// MODE 4: K-split partial (blockIdx.y = kz, base += kz*K, bm=0) — proven
//         r7/r10 path, 8 slices of K=128.
// ---------------------------------------------------------------------------
template<int MODE>
__global__ __launch_bounds__(256) void gemm_bt(
  const u16* __restrict__ A, int lda, const u16* __restrict__ Bw, int ldb, int K,
  const float* __restrict__ bias, float* __restrict__ outf, u16* __restrict__ outb,
  int ncols)
{
  const int bm=(MODE==4)? 0 : ((MODE==2)? blockIdx.x*128 : blockIdx.y*128);
  const int bn=(MODE==2)? blockIdx.y*128 : blockIdx.x*128;
  const int kz=(MODE==4)? blockIdx.y : 0;
  const u16* __restrict__ Ap=A +(size_t)kz*K;
  const u16* __restrict__ Bp=Bw+(size_t)kz*K;
  const int tid=threadIdx.x, lane=tid&63, wave=tid>>6;
  const int wr=(wave>>1)*64, wc=(wave&1)*64;
  __shared__ u16 As[128*32], Bs[128*32];
  f32x4 acc[4][4]={};
  const int srow=tid>>2, scol=(tid&3)*8;
  for(int k0=0;k0<K;k0+=32){
    gll16(Ap+(size_t)(bm+srow)*lda    +k0+scol, As+tid*8);
    gll16(Ap+(size_t)(bm+64+srow)*lda +k0+scol, As+2048+tid*8);
    gll16(Bp+(size_t)(bn+srow)*ldb    +k0+scol, Bs+tid*8);
    gll16(Bp+(size_t)(bn+64+srow)*ldb +k0+scol, Bs+2048+tid*8);
    __syncthreads();
    short8 af[4], bfr[4];
    const int ro=lane&15, ko=(lane>>4)*8;
#pragma unroll
    for(int m=0;m<4;++m) af[m]=*(const short8*)(As+(wr+m*16+ro)*32+ko);
#pragma unroll
    for(int n=0;n<4;++n) bfr[n]=*(const short8*)(Bs+(wc+n*16+ro)*32+ko);
#pragma unroll
    for(int m=0;m<4;++m)
#pragma unroll
      for(int n=0;n<4;++n) acc[m][n]=mfma16(af[m],bfr[n],acc[m][n]);
    __syncthreads();
  }
  asm volatile("s_nop 7\ns_nop 7\ns_nop 7");  // MFMA->VALU hazard guard
  const int ro4=(lane>>4)*4, co=lane&15;
#pragma unroll
  for(int m=0;m<4;++m)
#pragma unroll
    for(int n=0;n<4;++n)
#pragma unroll
      for(int j=0;j<4;++j){
        const int r=bm+wr+m*16+ro4+j, c=bn+wc+n*16+co;
        if constexpr (MODE==0)      outb[(size_t)r*ncols+c]=f2bf(acc[m][n][j]+bias[c]);
        else if constexpr (MODE==1) outf[(size_t)r*ncols+c]=acc[m][n][j]+bias[c];
        else if constexpr (MODE==2){ if (c<ncols) outf[(size_t)r*ncols+c]=acc[m][n][j]+bias[c]; }
        else                        outf[((size_t)kz*128+r)*ncols+c]=acc[m][n][j];
      }
}

// ---------------------------------------------------------------------------
extern "C" void kernel_launch(void* const* d_in, const int* in_sizes, int n_in,
                              void* d_out, int out_size, void* d_ws, size_t ws_size,
                              hipStream_t stream) {
  const float* feats   =(const float*)d_in[0];
  const int*   captions=(const int*)  d_in[1];
  const float* embW    =(const float*)d_in[2];
  const float* Wf_w    =(const float*)d_in[3];
  const float* Wf_b    =(const float*)d_in[4];
  const float* Wh_w    =(const float*)d_in[5];
  const float* Wh_b    =(const float*)d_in[6];
  const float* v_w     =(const float*)d_in[7];
  const float* v_b     =(const float*)d_in[8];
  const float* W_ih    =(const float*)d_in[9];
  const float* W_hh    =(const float*)d_in[10];
  const float* b_ih    =(const float*)d_in[11];
  const float* b_hh    =(const float*)d_in[12];
  const float* init_w  =(const float*)d_in[13];
  const float* init_b  =(const float*)d_in[14];
  const float* initc_w =(const float*)d_in[15];
  const float* initc_b =(const float*)d_in[16];
  const float* out_w   =(const float*)d_in[17];
  const float* out_b   =(const float*)d_in[18];
  float* out=(float*)d_out;
  char* ws=(char*)d_ws;

  u16*   feats_bf =(u16*)  (ws+0);
  u16*   fproj    =(u16*)  (ws+25690112);
  u16*   outw_bf  =(u16*)  (ws+51380224);
  u16*   Wc       =(u16*)  (ws+82182144);
  u16*   WihE     =(u16*)  (ws+86376448);
  u16*   Whw_bf   =(u16*)  (ws+88473600);
  u16*   Wf_bf    =(u16*)  (ws+88997888);
  u16*   embx     =(u16*)  (ws+89522176);
  u16*   h_all    =(u16*)  (ws+92143616);
  u16*   xs0      =(u16*)  (ws+94765056);
  float* gemb     =(float*)(ws+95289344);
  float* cbuf     =(float*)(ws+116260864);
  float* bias_comb=(float*)(ws+116785152);
  float* gpart    =(float*)(ws+116793344);  // 8 x 128 x 2048 f32 = 8 MB

  setup_cast<<<4096,256,0,stream>>>(feats,captions,embW,Wf_w,Wh_w,W_ih,W_hh,b_ih,b_hh,out_w,
                                    feats_bf,outw_bf,Wc,WihE,embx,Whw_bf,Wf_bf,bias_comb);
  prep<<<128,256,0,stream>>>(feats,init_w,init_b,initc_w,initc_b,xs0,cbuf);
  // fproj = feats_bf @ Wf^T + Wf_b  (25088 x 512, K=512) -> bf16
  gemm_bt<0><<<dim3(4,196),256,0,stream>>>(feats_bf,512,Wf_bf,512,512,
      Wf_b,nullptr,fproj,512);
  // gemb = embx @ WihE^T + (b_ih+b_hh)  (2560 x 2048, K=512) -> f32
  gemm_bt<1><<<dim3(16,20),256,0,stream>>>(embx,512,WihE,512,512,
      bias_comb,gemb,nullptr,2048);

  for(int t=0;t<20;++t){
    attn_step<<<128,1024,0,stream>>>(fproj,feats_bf,xs0,Whw_bf,Wh_b,v_w,v_b,
                                     gemb,gpart,cbuf,h_all,t);
    // gates partials: xs(128x1024) @ Wc^T(2048x1024), K-split 8x128 -> gpart
    gemm_bt<4><<<dim3(16,8),256,0,stream>>>(xs0,1024,Wc,1024,128,
        nullptr,gpart,nullptr,2048);
  }
  lstm_fin<<<128,512,0,stream>>>(gemb,gpart,cbuf,h_all);
  // logits = h_all @ out_w^T + out_b, transposed grid for out_w L2 reuse
  gemm_bt<2><<<dim3(20,235),256,0,stream>>>(h_all,512,outw_bf,512,512,
      out_b,out,nullptr,30000);
}